// Round 10
// baseline (1072.179 us; speedup 1.0000x reference)
//
#include <hip/hip_runtime.h>
#include <math.h>

static constexpr int F  = 128;    // channels per head / input dim
static constexpr int H  = 4;      // heads
static constexpr int HF = 512;    // H*F
static constexpr int NCP = 640;   // pre-GEMM cols: q-tilde(512) | S(128)
static constexpr int LAYERS = 4;

static constexpr int NB_WQK   = 64;
static constexpr int NB_WS    = 64;
static constexpr int NB_BPOST = 256;
static constexpr int NB_BIAS  = LAYERS;

typedef __attribute__((ext_vector_type(8))) short bf16x8;
typedef __attribute__((ext_vector_type(4))) float f32x4;

__device__ __forceinline__ unsigned short f2bf(float f) {
    union { float f; unsigned u; } v; v.f = f;
    unsigned r = (v.u + 0x7FFFu + ((v.u >> 16) & 1u)) >> 16;  // RNE
    return (unsigned short)r;
}
__device__ __forceinline__ float bf2f(unsigned short b) {
    union { unsigned u; float f; } v; v.u = ((unsigned)b) << 16;
    return v.f;
}

struct Params {
    const float* x; const int* src; const int* dst;
    const float* Wq; const float* bq; const float* Wk;
    const float* Wv; const float* bv; const float* Ws; const float* bs;
    float* out;
    float* Sb; float* biasPre; float* biasPost;
    unsigned short* h_bf; unsigned short* Qt; unsigned short* Agg;
    unsigned short* Bpre; unsigned short* Bpost;
    int* deg; int* row_ptr; int* csr_src;   // cursor = deg + N
    int* bar;                                // barrier slots (zeroed each call)
    int N, E;
};

// ---------------------------------------------------------------------------
// One-shot grid barrier. Slot idx used exactly once per launch; bar[] zeroed
// by hipMemsetAsync before the kernel. Device-scope atomics + __threadfence
// give cross-XCD visibility (same primitives grid.sync() uses).
// Deadlock-free because grid == exact co-residency capacity (see launch).
// ---------------------------------------------------------------------------
__device__ __forceinline__ void gbar(int idx, int nb, int* bar) {
    __syncthreads();
    if (threadIdx.x == 0) {
        __threadfence();                          // release my writes
        int* cnt = bar + idx * 2;
        int* flg = bar + idx * 2 + 1;
        int arrived = atomicAdd(cnt, 1);
        if (arrived == nb - 1) {
            __threadfence();
            atomicExch(flg, 1);                   // release all
        } else {
            while (atomicAdd(flg, 0) == 0) { __builtin_amdgcn_s_sleep(2); }
        }
        __threadfence();                          // acquire others' writes
    }
    __syncthreads();
}

// ---------------------------------------------------------------------------
// Phase 0 task: convert | wqk | pack_ws | pack_bpost | bias | zero
// ---------------------------------------------------------------------------
__device__ void prep_task(const Params& P, int t, int nConv, char* smem, float scale)
{
    const int tid = threadIdx.x;
    if (t < nConv) {
        int i = t * 256 + tid;
        int n4 = P.N * F / 4;
        if (i < n4) {
            float4 v = *(const float4*)(P.x + (size_t)i * 4);
            ushort4 o;
            o.x = f2bf(v.x); o.y = f2bf(v.y); o.z = f2bf(v.z); o.w = f2bf(v.w);
            *(ushort4*)(P.h_bf + (size_t)i * 4) = o;
        }
        return;
    }
    t -= nConv;
    if (t < NB_WQK) {
        float (*As)[33] = (float (*)[33])smem;
        float (*Bs)[33] = (float (*)[33])(smem + 64 * 33 * 4);
        const int bx = t & 1, by = (t >> 1) & 1, lh = t >> 2;
        const int l = lh >> 2, h = lh & 3;
        const int c0 = by * 64, k0 = bx * 64;
        const float* Ab = P.Wk + (size_t)l * 65536 + h * 128;
        const float* Bb = P.Wq + (size_t)l * 65536 + h * 128;
        const int tx = tid & 15, ty = tid >> 4;
        float acc[4][4] = {};
        for (int jj = 0; jj < 128; jj += 32) {
#pragma unroll
            for (int rep = 0; rep < 2; ++rep) {
                int f = tid + rep * 256;
                int r = f >> 3, j4 = (f & 7) * 4;
                float4 a = *(const float4*)(Ab + (size_t)(c0 + r) * 512 + jj + j4);
                As[r][j4 + 0] = a.x; As[r][j4 + 1] = a.y; As[r][j4 + 2] = a.z; As[r][j4 + 3] = a.w;
                float4 bb = *(const float4*)(Bb + (size_t)(k0 + r) * 512 + jj + j4);
                Bs[r][j4 + 0] = bb.x; Bs[r][j4 + 1] = bb.y; Bs[r][j4 + 2] = bb.z; Bs[r][j4 + 3] = bb.w;
            }
            __syncthreads();
#pragma unroll
            for (int j = 0; j < 32; ++j) {
                float a0 = As[ty * 4 + 0][j], a1 = As[ty * 4 + 1][j];
                float a2 = As[ty * 4 + 2][j], a3 = As[ty * 4 + 3][j];
                float b0 = Bs[tx * 4 + 0][j], b1 = Bs[tx * 4 + 1][j];
                float b2 = Bs[tx * 4 + 2][j], b3 = Bs[tx * 4 + 3][j];
                acc[0][0] += a0 * b0; acc[0][1] += a0 * b1; acc[0][2] += a0 * b2; acc[0][3] += a0 * b3;
                acc[1][0] += a1 * b0; acc[1][1] += a1 * b1; acc[1][2] += a1 * b2; acc[1][3] += a1 * b3;
                acc[2][0] += a2 * b0; acc[2][1] += a2 * b1; acc[2][2] += a2 * b2; acc[2][3] += a2 * b3;
                acc[3][0] += a3 * b0; acc[3][1] += a3 * b1; acc[3][2] += a3 * b2; acc[3][3] += a3 * b3;
            }
            __syncthreads();
        }
#pragma unroll
        for (int i = 0; i < 4; ++i)
#pragma unroll
            for (int u = 0; u < 4; ++u) {
                int c = c0 + ty * 4 + i;
                int k = k0 + tx * 4 + u;
                P.Bpre[(size_t)l * NCP * 128 + (size_t)(h * 128 + c) * 128 + k] = f2bf(scale * acc[i][u]);
            }
        return;
    }
    t -= NB_WQK;
    if (t < NB_WS) {
        unsigned short (*tt)[33] = (unsigned short (*)[33])smem;
        const int bx = t & 3, by = (t >> 2) & 3, l = t >> 4;
        const int k0 = bx * 32, n0 = by * 32;
        const int cx = tid & 31, ry = tid >> 5;
#pragma unroll
        for (int rr = 0; rr < 32; rr += 8) {
            int k = k0 + ry + rr;
            tt[ry + rr][cx] = f2bf(P.Ws[(size_t)l * 16384 + (size_t)k * 128 + n0 + cx]);
        }
        __syncthreads();
#pragma unroll
        for (int rr = 0; rr < 32; rr += 8) {
            int n = n0 + ry + rr;
            P.Bpre[(size_t)l * NCP * 128 + (size_t)(512 + n) * 128 + k0 + cx] = tt[cx][ry + rr];
        }
        __syncthreads();
        return;
    }
    t -= NB_WS;
    if (t < NB_BPOST) {
        unsigned short (*tt)[33] = (unsigned short (*)[33])smem;
        const int bx = t & 3, by = (t >> 2) & 3, lh = t >> 4;
        const int l = lh >> 2, h = lh & 3;
        const int ci0 = bx * 32, co0 = by * 32;
        const int cx = tid & 31, ry = tid >> 5;
#pragma unroll
        for (int rr = 0; rr < 32; rr += 8) {
            int ci = ci0 + ry + rr;
            tt[ry + rr][cx] = f2bf(0.25f * P.Wv[(size_t)l * 65536 + (size_t)ci * 512 + h * 128 + co0 + cx]);
        }
        __syncthreads();
#pragma unroll
        for (int rr = 0; rr < 32; rr += 8) {
            int co = co0 + ry + rr;
            P.Bpost[(size_t)l * 65536 + (size_t)co * 512 + h * 128 + ci0 + cx] = tt[cx][ry + rr];
        }
        __syncthreads();
        return;
    }
    t -= NB_BPOST;
    if (t < NB_BIAS) {
        const int l = t;
        for (int n = tid; n < NCP; n += 256) {
            float v;
            if (n < 512) {
                int h = n >> 7, c = n & 127;
                float s = 0.f;
                for (int j = 0; j < 128; ++j)
                    s += P.bq[(size_t)l * 512 + h * 128 + j] * P.Wk[(size_t)l * 65536 + (size_t)c * 512 + h * 128 + j];
                v = s * scale;
            } else {
                v = P.bs[(size_t)l * 128 + (n - 512)];
            }
            P.biasPre[(size_t)l * NCP + n] = v;
        }
        for (int c = tid; c < 128; c += 256) {
            float s = 0.f;
            for (int h = 0; h < 4; ++h) s += P.bv[(size_t)l * 512 + h * 128 + c];
            P.biasPost[(size_t)l * 128 + c] = 0.25f * s;
        }
        return;
    }
    t -= NB_BIAS;
    {
        int i = t * 256 + tid;
        if (i < 2 * P.N) P.deg[i] = 0;   // deg | cursor contiguous
    }
}

// ---------------------------------------------------------------------------
__device__ void scan_256(const int* __restrict__ deg, int* __restrict__ row_ptr,
                         int n, char* smem)
{
    int* wsum = (int*)smem;
    int* carry = wsum + 8;
    const int tid = threadIdx.x, lane = tid & 63, wid = tid >> 6;
    if (tid == 0) { *carry = 0; row_ptr[0] = 0; }
    __syncthreads();
    for (int base = 0; base < n; base += 256) {
        int i = base + tid;
        int x = (i < n) ? deg[i] : 0;
#pragma unroll
        for (int off = 1; off < 64; off <<= 1) {
            int tv = __shfl_up(x, off, 64);
            if (lane >= off) x += tv;
        }
        if (lane == 63) wsum[wid] = x;
        __syncthreads();
        if (tid == 0) {
            int s = *carry;
#pragma unroll
            for (int j = 0; j < 4; ++j) { int tv = wsum[j]; wsum[j] = s; s += tv; }
            *carry = s;
        }
        __syncthreads();
        int incl = x + wsum[wid];
        if (i < n) row_ptr[i + 1] = incl;
        __syncthreads();
    }
}

// ---------------------------------------------------------------------------
__device__ void gemm_pre_tile(const unsigned short* __restrict__ Abf,
                              const unsigned short* __restrict__ Bt,
                              const float* __restrict__ bias,
                              unsigned short* __restrict__ Qt,
                              float* __restrict__ Sb,
                              int M, int rowTile, int colTile, char* smem)
{
    typedef unsigned short (*tile_t)[72];
    tile_t As = (tile_t)smem;
    tile_t Bs = (tile_t)(smem + 128 * 72 * 2);

    const int tid = threadIdx.x;
    const int wave = tid >> 6, lane = tid & 63;
    const int lane16 = lane & 15, quad = lane >> 4;
    const int wr = wave >> 1, wc = wave & 1;
    const int row0 = rowTile * 128;
    const int col0 = colTile * 128;

    f32x4 acc[4][4] = {};

    for (int kk = 0; kk < 128; kk += 64) {
#pragma unroll
        for (int j = 0; j < 4; ++j) {
            int c = tid + j * 256;
            int r = c >> 3, c8 = (c & 7) * 8;
            bf16x8 v = {};
            if (row0 + r < M) v = *(const bf16x8*)(Abf + (size_t)(row0 + r) * 128 + kk + c8);
            *(bf16x8*)&As[r][c8] = v;
        }
#pragma unroll
        for (int j = 0; j < 4; ++j) {
            int c = tid + j * 256;
            int r = c >> 3, c8 = (c & 7) * 8;
            *(bf16x8*)&Bs[r][c8] = *(const bf16x8*)(Bt + (size_t)(col0 + r) * 128 + kk + c8);
        }
        __syncthreads();

#pragma unroll
        for (int ks = 0; ks < 2; ++ks) {
            bf16x8 a[4], b[4];
#pragma unroll
            for (int i = 0; i < 4; ++i)
                a[i] = *(const bf16x8*)&As[wr * 64 + i * 16 + lane16][ks * 32 + quad * 8];
#pragma unroll
            for (int i = 0; i < 4; ++i)
                b[i] = *(const bf16x8*)&Bs[wc * 64 + i * 16 + lane16][ks * 32 + quad * 8];
#pragma unroll
            for (int mi = 0; mi < 4; ++mi)
#pragma unroll
                for (int ni = 0; ni < 4; ++ni)
                    acc[mi][ni] = __builtin_amdgcn_mfma_f32_16x16x32_bf16(
                        a[mi], b[ni], acc[mi][ni], 0, 0, 0);
        }
        __syncthreads();
    }

#pragma unroll
    for (int mi = 0; mi < 4; ++mi) {
        int rowb = row0 + wr * 64 + mi * 16 + quad * 4;
#pragma unroll
        for (int ni = 0; ni < 4; ++ni) {
            int col = col0 + wc * 64 + ni * 16 + lane16;
            float bv = bias[col];
#pragma unroll
            for (int r = 0; r < 4; ++r) {
                int gr = rowb + r;
                if (gr < M) {
                    float v = acc[mi][ni][r] + bv;
                    if (col < 512) Qt[(size_t)gr * 512 + col] = f2bf(v);
                    else           Sb[(size_t)gr * 128 + (col - 512)] = v;
                }
            }
        }
    }
}

// ---------------------------------------------------------------------------
__device__ void attn_task(const unsigned short* __restrict__ Qt,
                          const unsigned short* __restrict__ Hb,
                          const int* __restrict__ row_ptr,
                          const int* __restrict__ csr_src,
                          unsigned short* __restrict__ Agg,
                          int N, int task)
{
    const int tid = threadIdx.x;
    const int wave = tid >> 6;
    const int g = (tid >> 4) & 3;
    const int l16 = tid & 15;
    const int node = task * 4 + wave;
    if (node >= N) return;

    const float NEG = -3e38f;

    float qf[4][8];
#pragma unroll
    for (int h = 0; h < 4; ++h) {
        bf16x8 qv = *(const bf16x8*)(Qt + (size_t)node * HF + h * F + l16 * 8);
#pragma unroll
        for (int j = 0; j < 8; ++j) qf[h][j] = bf2f((unsigned short)qv[j]);
    }
    const unsigned short* Hl = Hb + (size_t)l16 * 8;

    const int beg = row_ptr[node];
    const int end = row_ptr[node + 1];

    float m[4], z[4], acc[4][8];
#pragma unroll
    for (int h = 0; h < 4; ++h) { m[h] = NEG; z[h] = 0.f; }
#pragma unroll
    for (int h = 0; h < 4; ++h)
#pragma unroll
        for (int j = 0; j < 8; ++j) acc[h][j] = 0.f;

    for (int base = beg + g; base < end; base += 16) {
        const int i1 = base + 4, i2 = base + 8, i3 = base + 12;
        const bool v1 = i1 < end, v2 = i2 < end, v3 = i3 < end;
        int s0 = csr_src[base];
        int s1 = csr_src[v1 ? i1 : base];
        int s2 = csr_src[v2 ? i2 : base];
        int s3 = csr_src[v3 ? i3 : base];
        bf16x8 hb0 = *(const bf16x8*)(Hl + (size_t)s0 * F);
        bf16x8 hb1 = *(const bf16x8*)(Hl + (size_t)s1 * F);
        bf16x8 hb2 = *(const bf16x8*)(Hl + (size_t)s2 * F);
        bf16x8 hb3 = *(const bf16x8*)(Hl + (size_t)s3 * F);
        float hf[4][8];
#pragma unroll
        for (int j = 0; j < 8; ++j) {
            hf[0][j] = bf2f((unsigned short)hb0[j]);
            hf[1][j] = bf2f((unsigned short)hb1[j]);
            hf[2][j] = bf2f((unsigned short)hb2[j]);
            hf[3][j] = bf2f((unsigned short)hb3[j]);
        }
        float p[4][4];
#pragma unroll
        for (int e = 0; e < 4; ++e)
#pragma unroll
            for (int h = 0; h < 4; ++h) {
                float tv = 0.f;
#pragma unroll
                for (int j = 0; j < 8; ++j) tv += qf[h][j] * hf[e][j];
                p[e][h] = tv;
            }
#pragma unroll
        for (int off = 1; off < 16; off <<= 1)
#pragma unroll
            for (int e = 0; e < 4; ++e)
#pragma unroll
                for (int h = 0; h < 4; ++h)
                    p[e][h] += __shfl_xor(p[e][h], off, 64);
#pragma unroll
        for (int h = 0; h < 4; ++h) {
            if (!v1) p[1][h] = NEG;
            if (!v2) p[2][h] = NEG;
            if (!v3) p[3][h] = NEG;
        }
#pragma unroll
        for (int h = 0; h < 4; ++h) {
            float bm = fmaxf(fmaxf(p[0][h], p[1][h]), fmaxf(p[2][h], p[3][h]));
            float mn = fmaxf(m[h], bm);
            float rs = __expf(m[h] - mn);
            float w0 = __expf(p[0][h] - mn);
            float w1 = __expf(p[1][h] - mn);
            float w2 = __expf(p[2][h] - mn);
            float w3 = __expf(p[3][h] - mn);
            z[h] = z[h] * rs + (w0 + w1) + (w2 + w3);
#pragma unroll
            for (int j = 0; j < 8; ++j)
                acc[h][j] = acc[h][j] * rs
                          + w0 * hf[0][j] + w1 * hf[1][j]
                          + w2 * hf[2][j] + w3 * hf[3][j];
            m[h] = mn;
        }
    }

#pragma unroll
    for (int off = 16; off <= 32; off <<= 1) {
#pragma unroll
        for (int h = 0; h < 4; ++h) {
            float om = __shfl_xor(m[h], off, 64);
            float oz = __shfl_xor(z[h], off, 64);
            float M = fmaxf(m[h], om);
            float a = __expf(m[h] - M);
            float b = __expf(om - M);
            z[h] = z[h] * a + oz * b;
#pragma unroll
            for (int j = 0; j < 8; ++j) {
                float oa = __shfl_xor(acc[h][j], off, 64);
                acc[h][j] = acc[h][j] * a + oa * b;
            }
            m[h] = M;
        }
    }

    float i0 = (z[0] > 0.f) ? 1.f / z[0] : 0.f;
    float i1 = (z[1] > 0.f) ? 1.f / z[1] : 0.f;
    float i2 = (z[2] > 0.f) ? 1.f / z[2] : 0.f;
    float i3 = (z[3] > 0.f) ? 1.f / z[3] : 0.f;
    bf16x8 o;
    if (g == 0) {
#pragma unroll
        for (int j = 0; j < 8; ++j) o[j] = (short)f2bf(acc[0][j] * i0);
    } else if (g == 1) {
#pragma unroll
        for (int j = 0; j < 8; ++j) o[j] = (short)f2bf(acc[1][j] * i1);
    } else if (g == 2) {
#pragma unroll
        for (int j = 0; j < 8; ++j) o[j] = (short)f2bf(acc[2][j] * i2);
    } else {
#pragma unroll
        for (int j = 0; j < 8; ++j) o[j] = (short)f2bf(acc[3][j] * i3);
    }
    *(bf16x8*)(Agg + (size_t)node * HF + g * F + l16 * 8) = o;
}

// ---------------------------------------------------------------------------
__device__ void gemm_post_tile(const unsigned short* __restrict__ Agg,
                               const unsigned short* __restrict__ Bt,
                               const float* __restrict__ bias,
                               const float* __restrict__ Sb,
                               float* __restrict__ out_f,
                               unsigned short* __restrict__ out_bf,
                               int relu, int M, int rowTile, int colTile, char* smem)
{
    typedef unsigned short (*tile_t)[72];
    tile_t As = (tile_t)smem;
    tile_t Bs = (tile_t)(smem + 64 * 72 * 2);

    const int tid = threadIdx.x;
    const int wave = tid >> 6, lane = tid & 63;
    const int lane16 = lane & 15, quad = lane >> 4;
    const int row0 = rowTile * 64;
    const int col0 = colTile * 64;

    f32x4 acc[4] = {};

    for (int kk = 0; kk < 512; kk += 64) {
#pragma unroll
        for (int rep = 0; rep < 2; ++rep) {
            int c = tid + rep * 256;
            int r = c >> 3, c8 = (c & 7) * 8;
            bf16x8 v = {};
            if (row0 + r < M) v = *(const bf16x8*)(Agg + (size_t)(row0 + r) * 512 + kk + c8);
            *(bf16x8*)&As[r][c8] = v;
            *(bf16x8*)&Bs[r][c8] = *(const bf16x8*)(Bt + (size_t)(col0 + r) * 512 + kk + c8);
        }
        __syncthreads();

#pragma unroll
        for (int ks = 0; ks < 2; ++ks) {
            bf16x8 b = *(const bf16x8*)&Bs[wave * 16 + lane16][ks * 32 + quad * 8];
#pragma unroll
            for (int mt = 0; mt < 4; ++mt) {
                bf16x8 a = *(const bf16x8*)&As[mt * 16 + lane16][ks * 32 + quad * 8];
                acc[mt] = __builtin_amdgcn_mfma_f32_16x16x32_bf16(a, b, acc[mt], 0, 0, 0);
            }
        }
        __syncthreads();
    }

    const int col = col0 + wave * 16 + lane16;
    const float bcol = bias[col];
#pragma unroll
    for (int mt = 0; mt < 4; ++mt) {
#pragma unroll
        for (int r = 0; r < 4; ++r) {
            int row = row0 + mt * 16 + quad * 4 + r;
            if (row < M) {
                float v = acc[mt][r] + bcol + Sb[(size_t)row * 128 + col];
                if (relu) v = fmaxf(v, 0.f);
                if (out_f)  out_f[(size_t)row * 128 + col] = v;
                if (out_bf) out_bf[(size_t)row * 128 + col] = f2bf(v);
            }
        }
    }
}

// ---------------------------------------------------------------------------
// Persistent mega kernel: CSR + prep + 4 x (pre -> attn -> post), ONE dispatch,
// plain launch + hand-rolled one-shot grid barriers.
// ---------------------------------------------------------------------------
__global__ __launch_bounds__(256, 2) void mega_kernel(Params P)
{
    __shared__ __attribute__((aligned(16))) char smem[36992];

    const int nb = gridDim.x;
    const int bid = blockIdx.x;
    const int tid = threadIdx.x;
    const int N = P.N, E = P.E;
    const float scale = 0.08838834764831845f;   // 1/sqrt(128)
    int* cursor = P.deg + N;
    int* bar = P.bar;
    int bi = 0;   // barrier slot index (uniform control flow across all blocks)

    const int rb128 = (N + 127) / 128;
    const int rb64  = (N + 63) / 64;
    const int preTiles  = rb128 * (NCP / 128);
    const int postTiles = rb64 * 2;
    const int attnTasks = (N + 3) / 4;
    const int edgeT = (E + 255) / 256;

    // ---- phase 0: prep (convert, weight packs, biases) + zero deg/cursor
    {
        int nConv = (N * F / 4 + 255) / 256;
        int nZero = (2 * N + 255) / 256;
        int total = nConv + NB_WQK + NB_WS + NB_BPOST + NB_BIAS + nZero;
        for (int t = bid; t < total; t += nb)
            prep_task(P, t, nConv, smem, scale);
    }
    gbar(bi++, nb, bar);

    // ---- phase 1: histogram of dst  ∪  layer-0 pre-GEMM (independent)
    {
        int total = edgeT + preTiles;
        for (int t = bid; t < total; t += nb) {
            if (t < edgeT) {
                int e = t * 256 + tid;
                if (e < E) atomicAdd(&P.deg[P.dst[e]], 1);
            } else {
                int u = t - edgeT;
                gemm_pre_tile(P.h_bf, P.Bpre, P.biasPre, P.Qt, P.Sb, N,
                              u / (NCP / 128), u % (NCP / 128), smem);
            }
        }
    }
    gbar(bi++, nb, bar);

    // ---- phase 2: scan (block 0)
    if (bid == 0) scan_256(P.deg, P.row_ptr, N, smem);
    gbar(bi++, nb, bar);

    // ---- phase 3: scatter
    for (int t = bid; t < edgeT; t += nb) {
        int e = t * 256 + tid;
        if (e < E) {
            int d = P.dst[e];
            int pos = atomicAdd(&cursor[d], 1);
            P.csr_src[P.row_ptr[d] + pos] = P.src[e];
        }
    }
    gbar(bi++, nb, bar);

    // ---- layers
    for (int l = 0; l < LAYERS; ++l) {
        if (l > 0) {
            const unsigned short* BpreL = P.Bpre + (size_t)l * NCP * 128;
            const float* biasPreL = P.biasPre + (size_t)l * NCP;
            for (int t = bid; t < preTiles; t += nb)
                gemm_pre_tile(P.h_bf, BpreL, biasPreL, P.Qt, P.Sb, N,
                              t / (NCP / 128), t % (NCP / 128), smem);
            gbar(bi++, nb, bar);
        }

        for (int t = bid; t < attnTasks; t += nb)
            attn_task(P.Qt, P.h_bf, P.row_ptr, P.csr_src, P.Agg, N, t);
        gbar(bi++, nb, bar);

        float* out_f = (l == LAYERS - 1) ? P.out : nullptr;
        unsigned short* out_bf = (l == LAYERS - 1) ? nullptr : P.h_bf;
        int relu = (l == LAYERS - 1) ? 0 : 1;
        const unsigned short* BpostL = P.Bpost + (size_t)l * 128 * 512;
        const float* biasPostL = P.biasPost + (size_t)l * 128;
        for (int t = bid; t < postTiles; t += nb)
            gemm_post_tile(P.Agg, BpostL, biasPostL, P.Sb, out_f, out_bf,
                           relu, N, t / 2, t % 2, smem);
        if (l != LAYERS - 1) gbar(bi++, nb, bar);
    }
}

// ---------------------------------------------------------------------------
// Launch
// ---------------------------------------------------------------------------
extern "C" void kernel_launch(void* const* d_in, const int* in_sizes, int n_in,
                              void* d_out, int out_size, void* d_ws, size_t ws_size,
                              hipStream_t stream) {
    const float* x     = (const float*)d_in[0];
    const int*   ei    = (const int*)d_in[1];
    const float* Wq    = (const float*)d_in[2];
    const float* bq    = (const float*)d_in[3];
    const float* Wk    = (const float*)d_in[4];
    const float* Wv    = (const float*)d_in[6];
    const float* bv    = (const float*)d_in[7];
    const float* Wskip = (const float*)d_in[8];
    const float* bskip = (const float*)d_in[9];
    float* out = (float*)d_out;

    const int N = in_sizes[0] / F;       // 10000
    const int E = in_sizes[1] / 2;       // 160000

    // Workspace layout
    char* p = (char*)d_ws;
    float* Sb       = (float*)p;               p += (size_t)N * F * sizeof(float);
    float* biasPreP = (float*)p;               p += (size_t)LAYERS * NCP * sizeof(float);
    float* biasPostP= (float*)p;               p += (size_t)LAYERS * 128 * sizeof(float);
    unsigned short* h_bf  = (unsigned short*)p; p += (size_t)N * F * sizeof(unsigned short);
    unsigned short* Qt    = (unsigned short*)p; p += (size_t)N * HF * sizeof(unsigned short);
    unsigned short* AggB  = (unsigned short*)p; p += (size_t)N * HF * sizeof(unsigned short);
    unsigned short* BpreP = (unsigned short*)p; p += (size_t)LAYERS * NCP * 128 * sizeof(unsigned short);
    unsigned short* BpostP= (unsigned short*)p; p += (size_t)LAYERS * 128 * 512 * sizeof(unsigned short);
    int* deg     = (int*)p;                    p += (size_t)2 * N * sizeof(int);   // deg | cursor
    int* row_ptr = (int*)p;                    p += (size_t)(N + 1) * sizeof(int);
    int* csr_src = (int*)p;                    p += (size_t)E * sizeof(int);
    int* barP    = (int*)p;                    p += 64 * sizeof(int);              // 32 one-shot slots

    Params P;
    P.x = x; P.src = ei; P.dst = ei + E;
    P.Wq = Wq; P.bq = bq; P.Wk = Wk; P.Wv = Wv; P.bv = bv;
    P.Ws = Wskip; P.bs = bskip;
    P.out = out;
    P.Sb = Sb; P.biasPre = biasPreP; P.biasPost = biasPostP;
    P.h_bf = h_bf; P.Qt = Qt; P.Agg = AggB;
    P.Bpre = BpreP; P.Bpost = BpostP;
    P.deg = deg; P.row_ptr = row_ptr; P.csr_src = csr_src;
    P.bar = barP;
    P.N = N; P.E = E;

    // Zero the barrier slots (ws is re-poisoned to 0xAA before every call)
    hipMemsetAsync(barP, 0, 64 * sizeof(int), stream);

    // grid = exact co-residency capacity: 2 blocks/CU (forced by
    // __launch_bounds__(256,2): VGPR<=256; LDS 37KB*2=74KB<=160KB; 8 waves<=32)
    int dev = 0;
    hipGetDevice(&dev);
    int cu = 256;
    hipDeviceGetAttribute(&cu, hipDeviceAttributeMultiprocessorCount, dev);
    int grid = cu * 2;

    mega_kernel<<<grid, 256, 0, stream>>>(P);
}

// Round 11
// 455.201 us; speedup vs baseline: 2.3554x; 2.3554x over previous
//
#include <hip/hip_runtime.h>
#include <math.h>

static constexpr int F  = 128;    // channels per head / input dim
static constexpr int H  = 4;      // heads
static constexpr int HF = 512;    // H*F
static constexpr int NCP = 640;   // pre-GEMM cols: q-tilde(512) | S(128)
static constexpr int LAYERS = 4;

static constexpr int NB_CONV  = 1250;   // N*F/4 / 256
static constexpr int NB_WQK   = 64;
static constexpr int NB_WS    = 64;
static constexpr int NB_BPOST = 256;
static constexpr int NB_BIAS  = LAYERS;
static constexpr int NB_HIST  = 625;    // E/256
static constexpr int NB_PREP  = NB_CONV + NB_WQK + NB_WS + NB_BPOST + NB_BIAS + NB_HIST;

typedef __attribute__((ext_vector_type(8))) short bf16x8;
typedef __attribute__((ext_vector_type(4))) float f32x4;

__device__ __forceinline__ unsigned short f2bf(float f) {
    union { float f; unsigned u; } v; v.f = f;
    unsigned r = (v.u + 0x7FFFu + ((v.u >> 16) & 1u)) >> 16;  // RNE
    return (unsigned short)r;
}
__device__ __forceinline__ float bf2f(unsigned short b) {
    union { unsigned u; float f; } v; v.u = ((unsigned)b) << 16;
    return v.f;
}

// ---------------------------------------------------------------------------
// Prep + hist merged (all tasks depend only on the preceding memset):
// convert | wqk | pack_ws | pack_bpost | bias | hist
// ---------------------------------------------------------------------------
__global__ __launch_bounds__(256) void prep_hist_kernel(
    const float* __restrict__ x, unsigned short* __restrict__ h_bf, int n4,
    const float* __restrict__ Wq, const float* __restrict__ Wk,
    const float* __restrict__ Wv, const float* __restrict__ Ws,
    const float* __restrict__ bq, const float* __restrict__ bs, const float* __restrict__ bv,
    unsigned short* __restrict__ Bpre, unsigned short* __restrict__ Bpost,
    float* __restrict__ biasPre, float* __restrict__ biasPost,
    const int* __restrict__ dst, int* __restrict__ deg, int E, float scale)
{
    __shared__ __attribute__((aligned(16))) float smem[64 * 33 * 2];
    const int tid = threadIdx.x;
    int b = blockIdx.x;

    if (b < NB_CONV) {
        int i = b * 256 + tid;
        if (i < n4) {
            float4 v = *(const float4*)(x + (size_t)i * 4);
            ushort4 o;
            o.x = f2bf(v.x); o.y = f2bf(v.y); o.z = f2bf(v.z); o.w = f2bf(v.w);
            *(ushort4*)(h_bf + (size_t)i * 4) = o;
        }
        return;
    }
    b -= NB_CONV;
    if (b < NB_WQK) {
        float (*As)[33] = (float (*)[33])smem;
        float (*Bs)[33] = (float (*)[33])(smem + 64 * 33);
        const int bx = b & 1, by = (b >> 1) & 1, lh = b >> 2;
        const int l = lh >> 2, h = lh & 3;
        const int c0 = by * 64, k0 = bx * 64;
        const float* Ab = Wk + (size_t)l * 65536 + h * 128;
        const float* Bb = Wq + (size_t)l * 65536 + h * 128;
        const int tx = tid & 15, ty = tid >> 4;
        float acc[4][4] = {};
        for (int jj = 0; jj < 128; jj += 32) {
#pragma unroll
            for (int rep = 0; rep < 2; ++rep) {
                int f = tid + rep * 256;
                int r = f >> 3, j4 = (f & 7) * 4;
                float4 a = *(const float4*)(Ab + (size_t)(c0 + r) * 512 + jj + j4);
                As[r][j4 + 0] = a.x; As[r][j4 + 1] = a.y; As[r][j4 + 2] = a.z; As[r][j4 + 3] = a.w;
                float4 bb = *(const float4*)(Bb + (size_t)(k0 + r) * 512 + jj + j4);
                Bs[r][j4 + 0] = bb.x; Bs[r][j4 + 1] = bb.y; Bs[r][j4 + 2] = bb.z; Bs[r][j4 + 3] = bb.w;
            }
            __syncthreads();
#pragma unroll
            for (int j = 0; j < 32; ++j) {
                float a0 = As[ty * 4 + 0][j], a1 = As[ty * 4 + 1][j];
                float a2 = As[ty * 4 + 2][j], a3 = As[ty * 4 + 3][j];
                float b0 = Bs[tx * 4 + 0][j], b1 = Bs[tx * 4 + 1][j];
                float b2 = Bs[tx * 4 + 2][j], b3 = Bs[tx * 4 + 3][j];
                acc[0][0] += a0 * b0; acc[0][1] += a0 * b1; acc[0][2] += a0 * b2; acc[0][3] += a0 * b3;
                acc[1][0] += a1 * b0; acc[1][1] += a1 * b1; acc[1][2] += a1 * b2; acc[1][3] += a1 * b3;
                acc[2][0] += a2 * b0; acc[2][1] += a2 * b1; acc[2][2] += a2 * b2; acc[2][3] += a2 * b3;
                acc[3][0] += a3 * b0; acc[3][1] += a3 * b1; acc[3][2] += a3 * b2; acc[3][3] += a3 * b3;
            }
            __syncthreads();
        }
#pragma unroll
        for (int i = 0; i < 4; ++i)
#pragma unroll
            for (int u = 0; u < 4; ++u) {
                int c = c0 + ty * 4 + i;
                int k = k0 + tx * 4 + u;
                Bpre[(size_t)l * NCP * 128 + (size_t)(h * 128 + c) * 128 + k] = f2bf(scale * acc[i][u]);
            }
        return;
    }
    b -= NB_WQK;
    if (b < NB_WS) {
        unsigned short (*tt)[33] = (unsigned short (*)[33])smem;
        const int bx = b & 3, by = (b >> 2) & 3, l = b >> 4;
        const int k0 = bx * 32, n0 = by * 32;
        const int cx = tid & 31, ry = tid >> 5;
#pragma unroll
        for (int rr = 0; rr < 32; rr += 8) {
            int k = k0 + ry + rr;
            tt[ry + rr][cx] = f2bf(Ws[(size_t)l * 16384 + (size_t)k * 128 + n0 + cx]);
        }
        __syncthreads();
#pragma unroll
        for (int rr = 0; rr < 32; rr += 8) {
            int n = n0 + ry + rr;
            Bpre[(size_t)l * NCP * 128 + (size_t)(512 + n) * 128 + k0 + cx] = tt[cx][ry + rr];
        }
        return;
    }
    b -= NB_WS;
    if (b < NB_BPOST) {
        unsigned short (*tt)[33] = (unsigned short (*)[33])smem;
        const int bx = b & 3, by = (b >> 2) & 3, lh = b >> 4;
        const int l = lh >> 2, h = lh & 3;
        const int ci0 = bx * 32, co0 = by * 32;
        const int cx = tid & 31, ry = tid >> 5;
#pragma unroll
        for (int rr = 0; rr < 32; rr += 8) {
            int ci = ci0 + ry + rr;
            tt[ry + rr][cx] = f2bf(0.25f * Wv[(size_t)l * 65536 + (size_t)ci * 512 + h * 128 + co0 + cx]);
        }
        __syncthreads();
#pragma unroll
        for (int rr = 0; rr < 32; rr += 8) {
            int co = co0 + ry + rr;
            Bpost[(size_t)l * 65536 + (size_t)co * 512 + h * 128 + ci0 + cx] = tt[cx][ry + rr];
        }
        return;
    }
    b -= NB_BPOST;
    if (b < NB_BIAS) {
        const int l = b;
        for (int n = tid; n < NCP; n += 256) {
            float v;
            if (n < 512) {
                int h = n >> 7, c = n & 127;
                float s = 0.f;
                for (int j = 0; j < 128; ++j)
                    s += bq[(size_t)l * 512 + h * 128 + j] * Wk[(size_t)l * 65536 + (size_t)c * 512 + h * 128 + j];
                v = s * scale;
            } else {
                v = bs[(size_t)l * 128 + (n - 512)];
            }
            biasPre[(size_t)l * NCP + n] = v;
        }
        for (int c = tid; c < 128; c += 256) {
            float s = 0.f;
            for (int h = 0; h < 4; ++h) s += bv[(size_t)l * 512 + h * 128 + c];
            biasPost[(size_t)l * 128 + c] = 0.25f * s;
        }
        return;
    }
    b -= NB_BIAS;
    {   // histogram (deg zeroed by the memset that precedes this kernel)
        int e = b * 256 + tid;
        if (e < E) atomicAdd(&deg[dst[e]], 1);
    }
}

// ---------------------------------------------------------------------------
// Single-block 256-thread scan (verified round 10)
// ---------------------------------------------------------------------------
__device__ void scan_256(const int* __restrict__ deg, int* __restrict__ row_ptr,
                         int n, char* smem)
{
    int* wsum = (int*)smem;
    int* carry = wsum + 8;
    const int tid = threadIdx.x, lane = tid & 63, wid = tid >> 6;
    if (tid == 0) { *carry = 0; row_ptr[0] = 0; }
    __syncthreads();
    for (int base = 0; base < n; base += 256) {
        int i = base + tid;
        int x = (i < n) ? deg[i] : 0;
#pragma unroll
        for (int off = 1; off < 64; off <<= 1) {
            int tv = __shfl_up(x, off, 64);
            if (lane >= off) x += tv;
        }
        if (lane == 63) wsum[wid] = x;
        __syncthreads();
        if (tid == 0) {
            int s = *carry;
#pragma unroll
            for (int j = 0; j < 4; ++j) { int tv = wsum[j]; wsum[j] = s; s += tv; }
            *carry = s;
        }
        __syncthreads();
        int incl = x + wsum[wid];
        if (i < n) row_ptr[i + 1] = incl;
        __syncthreads();
    }
}

// ---------------------------------------------------------------------------
// 128x128 pre-GEMM tile (verified rounds 8/10)
// ---------------------------------------------------------------------------
__device__ void gemm_pre_tile(const unsigned short* __restrict__ Abf,
                              const unsigned short* __restrict__ Bt,
                              const float* __restrict__ bias,
                              unsigned short* __restrict__ Qt,
                              float* __restrict__ Sb,
                              int M, int rowTile, int colTile, char* smem)
{
    typedef unsigned short (*tile_t)[72];
    tile_t As = (tile_t)smem;
    tile_t Bs = (tile_t)(smem + 128 * 72 * 2);

    const int tid = threadIdx.x;
    const int wave = tid >> 6, lane = tid & 63;
    const int lane16 = lane & 15, quad = lane >> 4;
    const int wr = wave >> 1, wc = wave & 1;
    const int row0 = rowTile * 128;
    const int col0 = colTile * 128;

    f32x4 acc[4][4] = {};

    for (int kk = 0; kk < 128; kk += 64) {
#pragma unroll
        for (int j = 0; j < 4; ++j) {
            int c = tid + j * 256;
            int r = c >> 3, c8 = (c & 7) * 8;
            bf16x8 v = {};
            if (row0 + r < M) v = *(const bf16x8*)(Abf + (size_t)(row0 + r) * 128 + kk + c8);
            *(bf16x8*)&As[r][c8] = v;
        }
#pragma unroll
        for (int j = 0; j < 4; ++j) {
            int c = tid + j * 256;
            int r = c >> 3, c8 = (c & 7) * 8;
            *(bf16x8*)&Bs[r][c8] = *(const bf16x8*)(Bt + (size_t)(col0 + r) * 128 + kk + c8);
        }
        __syncthreads();

#pragma unroll
        for (int ks = 0; ks < 2; ++ks) {
            bf16x8 a[4], b[4];
#pragma unroll
            for (int i = 0; i < 4; ++i)
                a[i] = *(const bf16x8*)&As[wr * 64 + i * 16 + lane16][ks * 32 + quad * 8];
#pragma unroll
            for (int i = 0; i < 4; ++i)
                b[i] = *(const bf16x8*)&Bs[wc * 64 + i * 16 + lane16][ks * 32 + quad * 8];
#pragma unroll
            for (int mi = 0; mi < 4; ++mi)
#pragma unroll
                for (int ni = 0; ni < 4; ++ni)
                    acc[mi][ni] = __builtin_amdgcn_mfma_f32_16x16x32_bf16(
                        a[mi], b[ni], acc[mi][ni], 0, 0, 0);
        }
        __syncthreads();
    }

#pragma unroll
    for (int mi = 0; mi < 4; ++mi) {
        int rowb = row0 + wr * 64 + mi * 16 + quad * 4;
#pragma unroll
        for (int ni = 0; ni < 4; ++ni) {
            int col = col0 + wc * 64 + ni * 16 + lane16;
            float bv = bias[col];
#pragma unroll
            for (int r = 0; r < 4; ++r) {
                int gr = rowb + r;
                if (gr < M) {
                    float v = acc[mi][ni][r] + bv;
                    if (col < 512) Qt[(size_t)gr * 512 + col] = f2bf(v);
                    else           Sb[(size_t)gr * 128 + (col - 512)] = v;
                }
            }
        }
    }
}

// ---------------------------------------------------------------------------
// scan (block 0) + layer-0 pre-GEMM tiles (blocks 1..395) — independent work
// ---------------------------------------------------------------------------
__global__ __launch_bounds__(256) void scan_pre0_kernel(
    const int* __restrict__ deg, int* __restrict__ row_ptr, int N,
    const unsigned short* __restrict__ h_bf,
    const unsigned short* __restrict__ Bpre0, const float* __restrict__ biasPre0,
    unsigned short* __restrict__ Qt, float* __restrict__ Sb)
{
    __shared__ __attribute__((aligned(16))) char smem[128 * 72 * 2 * 2];
    if (blockIdx.x == 0) { scan_256(deg, row_ptr, N, smem); return; }
    int t = blockIdx.x - 1;
    gemm_pre_tile(h_bf, Bpre0, biasPre0, Qt, Sb, N, t / (NCP / 128), t % (NCP / 128), smem);
}

__global__ void scatter_kernel(const int* __restrict__ src, const int* __restrict__ dst,
                               const int* __restrict__ row_ptr, int* __restrict__ cursor,
                               int* __restrict__ csr_src, int E) {
    int e = blockIdx.x * blockDim.x + threadIdx.x;
    if (e < E) {
        int d = dst[e];
        int pos = atomicAdd(&cursor[d], 1);
        csr_src[row_ptr[d] + pos] = src[e];
    }
}

// ---------------------------------------------------------------------------
// One-pass flash attention aggregation (verified round 8, unchanged)
// ---------------------------------------------------------------------------
__global__ __launch_bounds__(256) void attn_agg(
    const unsigned short* __restrict__ Qt,
    const unsigned short* __restrict__ Hb,
    const int* __restrict__ row_ptr,
    const int* __restrict__ csr_src,
    unsigned short* __restrict__ Agg,
    int N)
{
    const int tid = threadIdx.x;
    const int wave = tid >> 6;
    const int g = (tid >> 4) & 3;
    const int l16 = tid & 15;
    const int node = blockIdx.x * 4 + wave;
    if (node >= N) return;

    const float NEG = -3e38f;

    float qf[4][8];
#pragma unroll
    for (int h = 0; h < 4; ++h) {
        bf16x8 qv = *(const bf16x8*)(Qt + (size_t)node * HF + h * F + l16 * 8);
#pragma unroll
        for (int j = 0; j < 8; ++j) qf[h][j] = bf2f((unsigned short)qv[j]);
    }
    const unsigned short* Hl = Hb + (size_t)l16 * 8;

    const int beg = row_ptr[node];
    const int end = row_ptr[node + 1];

    float m[4], z[4], acc[4][8];
#pragma unroll
    for (int h = 0; h < 4; ++h) { m[h] = NEG; z[h] = 0.f; }
#pragma unroll
    for (int h = 0; h < 4; ++h)
#pragma unroll
        for (int j = 0; j < 8; ++j) acc[h][j] = 0.f;

    for (int base = beg + g; base < end; base += 16) {
        const int i1 = base + 4, i2 = base + 8, i3 = base + 12;
        const bool v1 = i1 < end, v2 = i2 < end, v3 = i3 < end;
        int s0 = csr_src[base];
        int s1 = csr_src[v1 ? i1 : base];
        int s2 = csr_src[v2 ? i2 : base];
        int s3 = csr_src[v3 ? i3 : base];
        bf16x8 hb0 = *(const bf16x8*)(Hl + (size_t)s0 * F);
        bf16x8 hb1 = *(const bf16x8*)(Hl + (size_t)s1 * F);
        bf16x8 hb2 = *(const bf16x8*)(Hl + (size_t)s2 * F);
        bf16x8 hb3 = *(const bf16x8*)(Hl + (size_t)s3 * F);
        float hf[4][8];
#pragma unroll
        for (int j = 0; j < 8; ++j) {
            hf[0][j] = bf2f((unsigned short)hb0[j]);
            hf[1][j] = bf2f((unsigned short)hb1[j]);
            hf[2][j] = bf2f((unsigned short)hb2[j]);
            hf[3][j] = bf2f((unsigned short)hb3[j]);
        }
        float p[4][4];
#pragma unroll
        for (int e = 0; e < 4; ++e)
#pragma unroll
            for (int h = 0; h < 4; ++h) {
                float tv = 0.f;
#pragma unroll
                for (int j = 0; j < 8; ++j) tv += qf[h][j] * hf[e][j];
                p[e][h] = tv;
            }
#pragma unroll
        for (int off = 1; off < 16; off <<= 1)
#pragma unroll
            for (int e = 0; e < 4; ++e)
#pragma unroll
                for (int h = 0; h < 4; ++h)
                    p[e][h] += __shfl_xor(p[e][h], off, 64);
#pragma unroll
        for (int h = 0; h < 4; ++h) {
            if (!v1) p[1][h] = NEG;
            if (!v2) p[2][h] = NEG;
            if (!v3) p[3][h] = NEG;
        }
#pragma unroll
        for (int h = 0; h < 4; ++h) {
            float bm = fmaxf(fmaxf(p[0][h], p[1][h]), fmaxf(p[2][h], p[3][h]));
            float mn = fmaxf(m[h], bm);
            float rs = __expf(m[h] - mn);
            float w0 = __expf(p[0][h] - mn);
            float w1 = __expf(p[1][h] - mn);
            float w2 = __expf(p[2][h] - mn);
            float w3 = __expf(p[3][h] - mn);
            z[h] = z[h] * rs + (w0 + w1) + (w2 + w3);
#pragma unroll
            for (int j = 0; j < 8; ++j)
                acc[h][j] = acc[h][j] * rs
                          + w0 * hf[0][j] + w1 * hf[1][j]
                          + w2 * hf[2][j] + w3 * hf[3][j];
            m[h] = mn;
        }
    }

#pragma unroll
    for (int off = 16; off <= 32; off <<= 1) {
#pragma unroll
        for (int h = 0; h < 4; ++h) {
            float om = __shfl_xor(m[h], off, 64);
            float oz = __shfl_xor(z[h], off, 64);
            float M = fmaxf(m[h], om);
            float a = __expf(m[h] - M);
            float b = __expf(om - M);
            z[h] = z[h] * a + oz * b;
#pragma unroll
            for (int j = 0; j < 8; ++j) {
                float oa = __shfl_xor(acc[h][j], off, 64);
                acc[h][j] = acc[h][j] * a + oa * b;
            }
            m[h] = M;
        }
    }

    float i0 = (z[0] > 0.f) ? 1.f / z[0] : 0.f;
    float i1 = (z[1] > 0.f) ? 1.f / z[1] : 0.f;
    float i2 = (z[2] > 0.f) ? 1.f / z[2] : 0.f;
    float i3 = (z[3] > 0.f) ? 1.f / z[3] : 0.f;
    bf16x8 o;
    if (g == 0) {
#pragma unroll
        for (int j = 0; j < 8; ++j) o[j] = (short)f2bf(acc[0][j] * i0);
    } else if (g == 1) {
#pragma unroll
        for (int j = 0; j < 8; ++j) o[j] = (short)f2bf(acc[1][j] * i1);
    } else if (g == 2) {
#pragma unroll
        for (int j = 0; j < 8; ++j) o[j] = (short)f2bf(acc[2][j] * i2);
    } else {
#pragma unroll
        for (int j = 0; j < 8; ++j) o[j] = (short)f2bf(acc[3][j] * i3);
    }
    *(bf16x8*)(Agg + (size_t)node * HF + g * F + l16 * 8) = o;
}

// ---------------------------------------------------------------------------
// FUSED post_l + pre_{l+1}: per block, 64 rows.
// Phase A: h = relu(Agg@Bpost^T + biasPost + Sb) -> h_bf (global) + Hs (LDS).
// Phase B: {Qt|Sb} = Hs@Bpre^T + biasPre for the same rows (K=128 from LDS).
// Row-local in both phases -> no cross-block dependency.
// ---------------------------------------------------------------------------
__global__ __launch_bounds__(256) void fused_post_pre(
    const unsigned short* __restrict__ Agg,     // [N][512]
    const unsigned short* __restrict__ BtPost,  // [128][512]  layer l
    const float* __restrict__ biasPost,         // [128]       layer l
    const unsigned short* __restrict__ BtPre,   // [640][128]  layer l+1
    const float* __restrict__ biasPre,          // [640]       layer l+1
    float* __restrict__ Sb,                     // read (l) then overwritten (l+1)
    unsigned short* __restrict__ h_bf,          // [N][128] out (attn gathers)
    unsigned short* __restrict__ Qt,            // [N][512] out
    int M)
{
    __shared__ unsigned short Hs[64][136];                 // h tile, pitch 136 (16B-aligned rows)
    __shared__ __attribute__((aligned(16))) unsigned short Stg[128 * 72];

    const int tid = threadIdx.x;
    const int wave = tid >> 6, lane = tid & 63;
    const int lane16 = lane & 15, quad = lane >> 4;
    const int row0 = blockIdx.x * 64;

    typedef unsigned short (*t64)[72];
    t64 As = (t64)Stg;
    t64 Bs = (t64)(Stg + 64 * 72);

    // ---- phase A: post GEMM, two 64-col halves
#pragma unroll
    for (int ct = 0; ct < 2; ++ct) {
        const int col0 = ct * 64;
        f32x4 acc[4] = {};
        for (int kk = 0; kk < 512; kk += 64) {
#pragma unroll
            for (int rep = 0; rep < 2; ++rep) {
                int c = tid + rep * 256;
                int r = c >> 3, c8 = (c & 7) * 8;
                bf16x8 v = {};
                if (row0 + r < M) v = *(const bf16x8*)(Agg + (size_t)(row0 + r) * 512 + kk + c8);
                *(bf16x8*)&As[r][c8] = v;
                *(bf16x8*)&Bs[r][c8] = *(const bf16x8*)(BtPost + (size_t)(col0 + r) * 512 + kk + c8);
            }
            __syncthreads();
#pragma unroll
            for (int ks = 0; ks < 2; ++ks) {
                bf16x8 b = *(const bf16x8*)&Bs[wave * 16 + lane16][ks * 32 + quad * 8];
#pragma unroll
                for (int mt = 0; mt < 4; ++mt) {
                    bf16x8 a = *(const bf16x8*)&As[mt * 16 + lane16][ks * 32 + quad * 8];
                    acc[mt] = __builtin_amdgcn_mfma_f32_16x16x32_bf16(a, b, acc[mt], 0, 0, 0);
                }
            }
            __syncthreads();
        }
        const int col = col0 + wave * 16 + lane16;
        const float bcol = biasPost[col];
#pragma unroll
        for (int mt = 0; mt < 4; ++mt) {
#pragma unroll
            for (int r = 0; r < 4; ++r) {
                int lrow = mt * 16 + quad * 4 + r;
                int row = row0 + lrow;
                if (row < M) {
                    float v = acc[mt][r] + bcol + Sb[(size_t)row * 128 + col];
                    v = fmaxf(v, 0.f);                      // ReLU (inner layers only)
                    unsigned short us = f2bf(v);
                    h_bf[(size_t)row * 128 + col] = us;
                    Hs[lrow][col] = us;
                } else {
                    Hs[lrow][col] = 0;
                }
            }
        }
    }
    __syncthreads();

    // ---- phase B: pre GEMM from Hs, 5 col-tiles of 128
    t64 B2 = (t64)Stg;   // 128 rows x 64 k per chunk
    for (int nt = 0; nt < 5; ++nt) {
        const int col0 = nt * 128;
        f32x4 acc2[8] = {};
        for (int kk = 0; kk < 128; kk += 64) {
#pragma unroll
            for (int rep = 0; rep < 4; ++rep) {
                int c = tid + rep * 256;
                int r = c >> 3, c8 = (c & 7) * 8;
                *(bf16x8*)&B2[r][c8] = *(const bf16x8*)(BtPre + (size_t)(col0 + r) * 128 + kk + c8);
            }
            __syncthreads();
#pragma unroll
            for (int ks = 0; ks < 2; ++ks) {
                bf16x8 a = *(const bf16x8*)&Hs[wave * 16 + lane16][kk + ks * 32 + quad * 8];
#pragma unroll
                for (int ni = 0; ni < 8; ++ni) {
                    bf16x8 b = *(const bf16x8*)&B2[ni * 16 + lane16][ks * 32 + quad * 8];
                    acc2[ni] = __builtin_amdgcn_mfma_f32_16x16x32_bf16(a, b, acc2[ni], 0, 0, 0);
                }
            }
            __syncthreads();
        }
#pragma unroll
        for (int ni = 0; ni < 8; ++ni) {
            int col = col0 + ni * 16 + lane16;
            float bv = biasPre[col];
#pragma unroll
            for (int r = 0; r < 4; ++r) {
                int row = row0 + wave * 16 + quad * 4 + r;
                if (row < M) {
                    float v = acc2[ni][r] + bv;
                    if (col < 512) Qt[(size_t)row * 512 + col] = f2bf(v);
                    else           Sb[(size_t)row * 128 + (col - 512)] = v;
                }
            }
        }
    }
}

// ---------------------------------------------------------------------------
// Final post GEMM (layer 3): out = Agg@Bpost^T + biasPost + Sb  (no ReLU)
// ---------------------------------------------------------------------------
__global__ __launch_bounds__(256) void gemm_post_final(
    const unsigned short* __restrict__ Agg,
    const unsigned short* __restrict__ Bt,
    const float* __restrict__ bias,
    const float* __restrict__ Sb,
    float* __restrict__ out, int M)
{
    __shared__ __attribute__((aligned(16))) unsigned short Stg[128 * 72];
    typedef unsigned short (*t64)[72];
    t64 As = (t64)Stg;
    t64 Bs = (t64)(Stg + 64 * 72);

    const int tid = threadIdx.x;
    const int wave = tid >> 6, lane = tid & 63;
    const int lane16 = lane & 15, quad = lane >> 4;
    const int row0 = blockIdx.y * 64;
    const int col0 = blockIdx.x * 64;

    f32x4 acc[4] = {};

    for (int kk = 0; kk < 512; kk += 64) {
#pragma unroll
        for (int rep = 0; rep < 2; ++rep) {
            int c = tid + rep * 256;
            int r = c >> 3, c8 = (c & 7) * 8;
            bf16x8 v = {};
            if (row0 + r < M) v = *(const bf16x8*)(Agg + (size_t)(row0 + r) * 512 + kk + c8);
            *(bf16x8*)&As[r][c8] = v;
            *(bf16x8*)&Bs[r][c8] = *(const bf16x8*)(Bt + (size_t)(col0 + r) * 512 + kk + c8);
        }
        __syncthreads();

#pragma unroll
        for (int ks = 0; ks < 2; ++ks) {
            bf16x8 b = *(const bf16x8*)&Bs[wave * 16 + lane16][ks * 32 + quad * 8];
#pragma unroll
            for (int mt = 0; mt < 4; ++mt) {
                bf16x8 a = *(const bf16x8*)&As[mt * 16 + lane16][ks * 32 + quad * 8];
                acc[mt] = __builtin_amdgcn_mfma_f32_16x16x32_bf16(a, b, acc[mt], 0, 0, 0);
            }
        }
        __syncthreads();
    }

    const int col = col0 + wave * 16 + lane16;
    const float bcol = bias[col];
#pragma unroll
    for (int mt = 0; mt < 4; ++mt) {
#pragma unroll
        for (int r = 0; r < 4; ++r) {
            int row = row0 + mt * 16 + quad * 4 + r;
            if (row < M)
                out[(size_t)row * 128 + col] = acc[mt][r] + bcol + Sb[(size_t)row * 128 + col];
        }
    }
}

// ---------------------------------------------------------------------------
// Launch: 12 dispatches (memset + 11 kernels)
// ---------------------------------------------------------------------------
extern "C" void kernel_launch(void* const* d_in, const int* in_sizes, int n_in,
                              void* d_out, int out_size, void* d_ws, size_t ws_size,
                              hipStream_t stream) {
    const float* x     = (const float*)d_in[0];
    const int*   ei    = (const int*)d_in[1];
    const float* Wq    = (const float*)d_in[2];
    const float* bq    = (const float*)d_in[3];
    const float* Wk    = (const float*)d_in[4];
    const float* Wv    = (const float*)d_in[6];
    const float* bv    = (const float*)d_in[7];
    const float* Wskip = (const float*)d_in[8];
    const float* bskip = (const float*)d_in[9];
    float* out = (float*)d_out;

    const int N = in_sizes[0] / F;       // 10000
    const int E = in_sizes[1] / 2;       // 160000
    const float scale = 0.08838834764831845f;   // 1/sqrt(128)

    const int* src = ei;
    const int* dst = ei + E;

    // Workspace layout
    char* p = (char*)d_ws;
    float* Sb       = (float*)p;               p += (size_t)N * F * sizeof(float);
    float* biasPreP = (float*)p;               p += (size_t)LAYERS * NCP * sizeof(float);
    float* biasPostP= (float*)p;               p += (size_t)LAYERS * 128 * sizeof(float);
    unsigned short* h_bf  = (unsigned short*)p; p += (size_t)N * F * sizeof(unsigned short);
    unsigned short* Qt    = (unsigned short*)p; p += (size_t)N * HF * sizeof(unsigned short);
    unsigned short* AggB  = (unsigned short*)p; p += (size_t)N * HF * sizeof(unsigned short);
    unsigned short* BpreP = (unsigned short*)p; p += (size_t)LAYERS * NCP * 128 * sizeof(unsigned short);
    unsigned short* BpostP= (unsigned short*)p; p += (size_t)LAYERS * 128 * 512 * sizeof(unsigned short);
    int* deg     = (int*)p;                    p += (size_t)2 * N * sizeof(int);   // deg | cursor
    int* row_ptr = (int*)p;                    p += (size_t)(N + 1) * sizeof(int);
    int* csr_src = (int*)p;

    int* cursor = deg + N;

    // 1. zero deg+cursor (hist/scatter prerequisites)
    hipMemsetAsync(deg, 0, 2 * (size_t)N * sizeof(int), stream);

    // 2. prep (converts, weight packs, biases) + hist, one kernel
    prep_hist_kernel<<<NB_PREP, 256, 0, stream>>>(
        x, h_bf, N * F / 4, Wq, Wk, Wv, Wskip, bq, bskip, bv,
        BpreP, BpostP, biasPreP, biasPostP, dst, deg, E, scale);

    const int rowBlocks128 = (N + 127) / 128;
    const int rowBlocks64  = (N + 63) / 64;
    const int preTiles = rowBlocks128 * (NCP / 128);
    const int attnBlocks = (N + 3) / 4;

    // 3. scan (block 0) + layer-0 pre-GEMM (blocks 1..preTiles)
    scan_pre0_kernel<<<preTiles + 1, 256, 0, stream>>>(
        deg, row_ptr, N, h_bf, BpreP, biasPreP, Qt, Sb);

    // 4. scatter
    scatter_kernel<<<(E + 255) / 256, 256, 0, stream>>>(src, dst, row_ptr, cursor, csr_src, E);

    // 5..11: attn_0, [post_l + pre_{l+1}] x3 interleaved with attn, final post
    attn_agg<<<attnBlocks, 256, 0, stream>>>(Qt, h_bf, row_ptr, csr_src, AggB, N);

    for (int l = 0; l < LAYERS - 1; ++l) {
        fused_post_pre<<<rowBlocks64, 256, 0, stream>>>(
            AggB,
            BpostP + (size_t)l * 128 * 512, biasPostP + (size_t)l * 128,
            BpreP + (size_t)(l + 1) * NCP * 128, biasPreP + (size_t)(l + 1) * NCP,
            Sb, h_bf, Qt, N);
        attn_agg<<<attnBlocks, 256, 0, stream>>>(Qt, h_bf, row_ptr, csr_src, AggB, N);
    }

    gemm_post_final<<<dim3(2, rowBlocks64), 256, 0, stream>>>(
        AggB, BpostP + (size_t)3 * 128 * 512, biasPostP + (size_t)3 * 128,
        Sb, out, N);
}

// Round 12
// 429.828 us; speedup vs baseline: 2.4944x; 1.0590x over previous
//
#include <hip/hip_runtime.h>
#include <math.h>

static constexpr int F  = 128;    // channels per head / input dim
static constexpr int H  = 4;      // heads
static constexpr int HF = 512;    // H*F
static constexpr int NCP = 640;   // pre-GEMM cols: q-tilde(512) | S(128)
static constexpr int LAYERS = 4;

static constexpr int NB_CONV  = 1250;   // N*F/4 / 256
static constexpr int NB_WQK   = 64;
static constexpr int NB_WS    = 64;
static constexpr int NB_BPOST = 256;
static constexpr int NB_BIAS  = LAYERS;
static constexpr int NB_HIST  = 625;    // E/256
static constexpr int NB_PREP  = NB_CONV + NB_WQK + NB_WS + NB_BPOST + NB_BIAS + NB_HIST;

typedef __attribute__((ext_vector_type(8))) short bf16x8;
typedef __attribute__((ext_vector_type(4))) float f32x4;

__device__ __forceinline__ unsigned short f2bf(float f) {
    union { float f; unsigned u; } v; v.f = f;
    unsigned r = (v.u + 0x7FFFu + ((v.u >> 16) & 1u)) >> 16;  // RNE
    return (unsigned short)r;
}
__device__ __forceinline__ float bf2f(unsigned short b) {
    union { unsigned u; float f; } v; v.u = ((unsigned)b) << 16;
    return v.f;
}

// ---------------------------------------------------------------------------
// Prep + hist merged: convert | wqk | pack_ws | pack_bpost | bias | hist
// (all tasks depend only on the preceding memset; 2323 blocks)
// ---------------------------------------------------------------------------
__global__ __launch_bounds__(256) void prep_hist_kernel(
    const float* __restrict__ x, unsigned short* __restrict__ h_bf, int n4,
    const float* __restrict__ Wq, const float* __restrict__ Wk,
    const float* __restrict__ Wv, const float* __restrict__ Ws,
    const float* __restrict__ bq, const float* __restrict__ bs, const float* __restrict__ bv,
    unsigned short* __restrict__ Bpre, unsigned short* __restrict__ Bpost,
    float* __restrict__ biasPre, float* __restrict__ biasPost,
    const int* __restrict__ dst, int* __restrict__ deg, int E, float scale)
{
    __shared__ __attribute__((aligned(16))) float smem[64 * 33 * 2];
    const int tid = threadIdx.x;
    int b = blockIdx.x;

    if (b < NB_CONV) {
        int i = b * 256 + tid;
        if (i < n4) {
            float4 v = *(const float4*)(x + (size_t)i * 4);
            ushort4 o;
            o.x = f2bf(v.x); o.y = f2bf(v.y); o.z = f2bf(v.z); o.w = f2bf(v.w);
            *(ushort4*)(h_bf + (size_t)i * 4) = o;
        }
        return;
    }
    b -= NB_CONV;
    if (b < NB_WQK) {
        float (*As)[33] = (float (*)[33])smem;
        float (*Bs)[33] = (float (*)[33])(smem + 64 * 33);
        const int bx = b & 1, by = (b >> 1) & 1, lh = b >> 2;
        const int l = lh >> 2, h = lh & 3;
        const int c0 = by * 64, k0 = bx * 64;
        const float* Ab = Wk + (size_t)l * 65536 + h * 128;
        const float* Bb = Wq + (size_t)l * 65536 + h * 128;
        const int tx = tid & 15, ty = tid >> 4;
        float acc[4][4] = {};
        for (int jj = 0; jj < 128; jj += 32) {
#pragma unroll
            for (int rep = 0; rep < 2; ++rep) {
                int f = tid + rep * 256;
                int r = f >> 3, j4 = (f & 7) * 4;
                float4 a = *(const float4*)(Ab + (size_t)(c0 + r) * 512 + jj + j4);
                As[r][j4 + 0] = a.x; As[r][j4 + 1] = a.y; As[r][j4 + 2] = a.z; As[r][j4 + 3] = a.w;
                float4 bb = *(const float4*)(Bb + (size_t)(k0 + r) * 512 + jj + j4);
                Bs[r][j4 + 0] = bb.x; Bs[r][j4 + 1] = bb.y; Bs[r][j4 + 2] = bb.z; Bs[r][j4 + 3] = bb.w;
            }
            __syncthreads();
#pragma unroll
            for (int j = 0; j < 32; ++j) {
                float a0 = As[ty * 4 + 0][j], a1 = As[ty * 4 + 1][j];
                float a2 = As[ty * 4 + 2][j], a3 = As[ty * 4 + 3][j];
                float b0 = Bs[tx * 4 + 0][j], b1 = Bs[tx * 4 + 1][j];
                float b2 = Bs[tx * 4 + 2][j], b3 = Bs[tx * 4 + 3][j];
                acc[0][0] += a0 * b0; acc[0][1] += a0 * b1; acc[0][2] += a0 * b2; acc[0][3] += a0 * b3;
                acc[1][0] += a1 * b0; acc[1][1] += a1 * b1; acc[1][2] += a1 * b2; acc[1][3] += a1 * b3;
                acc[2][0] += a2 * b0; acc[2][1] += a2 * b1; acc[2][2] += a2 * b2; acc[2][3] += a2 * b3;
                acc[3][0] += a3 * b0; acc[3][1] += a3 * b1; acc[3][2] += a3 * b2; acc[3][3] += a3 * b3;
            }
            __syncthreads();
        }
#pragma unroll
        for (int i = 0; i < 4; ++i)
#pragma unroll
            for (int u = 0; u < 4; ++u) {
                int c = c0 + ty * 4 + i;
                int k = k0 + tx * 4 + u;
                Bpre[(size_t)l * NCP * 128 + (size_t)(h * 128 + c) * 128 + k] = f2bf(scale * acc[i][u]);
            }
        return;
    }
    b -= NB_WQK;
    if (b < NB_WS) {
        unsigned short (*tt)[33] = (unsigned short (*)[33])smem;
        const int bx = b & 3, by = (b >> 2) & 3, l = b >> 4;
        const int k0 = bx * 32, n0 = by * 32;
        const int cx = tid & 31, ry = tid >> 5;
#pragma unroll
        for (int rr = 0; rr < 32; rr += 8) {
            int k = k0 + ry + rr;
            tt[ry + rr][cx] = f2bf(Ws[(size_t)l * 16384 + (size_t)k * 128 + n0 + cx]);
        }
        __syncthreads();
#pragma unroll
        for (int rr = 0; rr < 32; rr += 8) {
            int n = n0 + ry + rr;
            Bpre[(size_t)l * NCP * 128 + (size_t)(512 + n) * 128 + k0 + cx] = tt[cx][ry + rr];
        }
        return;
    }
    b -= NB_WS;
    if (b < NB_BPOST) {
        unsigned short (*tt)[33] = (unsigned short (*)[33])smem;
        const int bx = b & 3, by = (b >> 2) & 3, lh = b >> 4;
        const int l = lh >> 2, h = lh & 3;
        const int ci0 = bx * 32, co0 = by * 32;
        const int cx = tid & 31, ry = tid >> 5;
#pragma unroll
        for (int rr = 0; rr < 32; rr += 8) {
            int ci = ci0 + ry + rr;
            tt[ry + rr][cx] = f2bf(0.25f * Wv[(size_t)l * 65536 + (size_t)ci * 512 + h * 128 + co0 + cx]);
        }
        __syncthreads();
#pragma unroll
        for (int rr = 0; rr < 32; rr += 8) {
            int co = co0 + ry + rr;
            Bpost[(size_t)l * 65536 + (size_t)co * 512 + h * 128 + ci0 + cx] = tt[cx][ry + rr];
        }
        return;
    }
    b -= NB_BPOST;
    if (b < NB_BIAS) {
        const int l = b;
        for (int n = tid; n < NCP; n += 256) {
            float v;
            if (n < 512) {
                int h = n >> 7, c = n & 127;
                float s = 0.f;
                for (int j = 0; j < 128; ++j)
                    s += bq[(size_t)l * 512 + h * 128 + j] * Wk[(size_t)l * 65536 + (size_t)c * 512 + h * 128 + j];
                v = s * scale;
            } else {
                v = bs[(size_t)l * 128 + (n - 512)];
            }
            biasPre[(size_t)l * NCP + n] = v;
        }
        for (int c = tid; c < 128; c += 256) {
            float s = 0.f;
            for (int h = 0; h < 4; ++h) s += bv[(size_t)l * 512 + h * 128 + c];
            biasPost[(size_t)l * 128 + c] = 0.25f * s;
        }
        return;
    }
    b -= NB_BIAS;
    {   // histogram (deg zeroed by the preceding memset)
        int e = b * 256 + tid;
        if (e < E) atomicAdd(&deg[dst[e]], 1);
    }
}

// ---------------------------------------------------------------------------
// Single-block 256-thread scan (verified rounds 10/11)
// ---------------------------------------------------------------------------
__device__ void scan_256(const int* __restrict__ deg, int* __restrict__ row_ptr,
                         int n, char* smem)
{
    int* wsum = (int*)smem;
    int* carry = wsum + 8;
    const int tid = threadIdx.x, lane = tid & 63, wid = tid >> 6;
    if (tid == 0) { *carry = 0; row_ptr[0] = 0; }
    __syncthreads();
    for (int base = 0; base < n; base += 256) {
        int i = base + tid;
        int x = (i < n) ? deg[i] : 0;
#pragma unroll
        for (int off = 1; off < 64; off <<= 1) {
            int tv = __shfl_up(x, off, 64);
            if (lane >= off) x += tv;
        }
        if (lane == 63) wsum[wid] = x;
        __syncthreads();
        if (tid == 0) {
            int s = *carry;
#pragma unroll
            for (int j = 0; j < 4; ++j) { int tv = wsum[j]; wsum[j] = s; s += tv; }
            *carry = s;
        }
        __syncthreads();
        int incl = x + wsum[wid];
        if (i < n) row_ptr[i + 1] = incl;
        __syncthreads();
    }
}

// ---------------------------------------------------------------------------
// 128x128 pre-GEMM tile (verified rounds 8/10/11)
// ---------------------------------------------------------------------------
__device__ void gemm_pre_tile(const unsigned short* __restrict__ Abf,
                              const unsigned short* __restrict__ Bt,
                              const float* __restrict__ bias,
                              unsigned short* __restrict__ Qt,
                              float* __restrict__ Sb,
                              int M, int rowTile, int colTile, char* smem)
{
    typedef unsigned short (*tile_t)[72];
    tile_t As = (tile_t)smem;
    tile_t Bs = (tile_t)(smem + 128 * 72 * 2);

    const int tid = threadIdx.x;
    const int wave = tid >> 6, lane = tid & 63;
    const int lane16 = lane & 15, quad = lane >> 4;
    const int wr = wave >> 1, wc = wave & 1;
    const int row0 = rowTile * 128;
    const int col0 = colTile * 128;

    f32x4 acc[4][4] = {};

    for (int kk = 0; kk < 128; kk += 64) {
#pragma unroll
        for (int j = 0; j < 4; ++j) {
            int c = tid + j * 256;
            int r = c >> 3, c8 = (c & 7) * 8;
            bf16x8 v = {};
            if (row0 + r < M) v = *(const bf16x8*)(Abf + (size_t)(row0 + r) * 128 + kk + c8);
            *(bf16x8*)&As[r][c8] = v;
        }
#pragma unroll
        for (int j = 0; j < 4; ++j) {
            int c = tid + j * 256;
            int r = c >> 3, c8 = (c & 7) * 8;
            *(bf16x8*)&Bs[r][c8] = *(const bf16x8*)(Bt + (size_t)(col0 + r) * 128 + kk + c8);
        }
        __syncthreads();

#pragma unroll
        for (int ks = 0; ks < 2; ++ks) {
            bf16x8 a[4], b[4];
#pragma unroll
            for (int i = 0; i < 4; ++i)
                a[i] = *(const bf16x8*)&As[wr * 64 + i * 16 + lane16][ks * 32 + quad * 8];
#pragma unroll
            for (int i = 0; i < 4; ++i)
                b[i] = *(const bf16x8*)&Bs[wc * 64 + i * 16 + lane16][ks * 32 + quad * 8];
#pragma unroll
            for (int mi = 0; mi < 4; ++mi)
#pragma unroll
                for (int ni = 0; ni < 4; ++ni)
                    acc[mi][ni] = __builtin_amdgcn_mfma_f32_16x16x32_bf16(
                        a[mi], b[ni], acc[mi][ni], 0, 0, 0);
        }
        __syncthreads();
    }

#pragma unroll
    for (int mi = 0; mi < 4; ++mi) {
        int rowb = row0 + wr * 64 + mi * 16 + quad * 4;
#pragma unroll
        for (int ni = 0; ni < 4; ++ni) {
            int col = col0 + wc * 64 + ni * 16 + lane16;
            float bv = bias[col];
#pragma unroll
            for (int r = 0; r < 4; ++r) {
                int gr = rowb + r;
                if (gr < M) {
                    float v = acc[mi][ni][r] + bv;
                    if (col < 512) Qt[(size_t)gr * 512 + col] = f2bf(v);
                    else           Sb[(size_t)gr * 128 + (col - 512)] = v;
                }
            }
        }
    }
}

// ---------------------------------------------------------------------------
// scan (block 0) + layer-0 pre-GEMM tiles (blocks 1..395)
// ---------------------------------------------------------------------------
__global__ __launch_bounds__(256) void scan_pre0_kernel(
    const int* __restrict__ deg, int* __restrict__ row_ptr, int N,
    const unsigned short* __restrict__ h_bf,
    const unsigned short* __restrict__ Bpre0, const float* __restrict__ biasPre0,
    unsigned short* __restrict__ Qt, float* __restrict__ Sb)
{
    __shared__ __attribute__((aligned(16))) char smem[128 * 72 * 2 * 2];
    if (blockIdx.x == 0) { scan_256(deg, row_ptr, N, smem); return; }
    int t = blockIdx.x - 1;
    gemm_pre_tile(h_bf, Bpre0, biasPre0, Qt, Sb, N, t / (NCP / 128), t % (NCP / 128), smem);
}

// Standalone pre-GEMM for layers 1..3 (395 blocks)
__global__ __launch_bounds__(256) void gemm_pre_kernel(
    const unsigned short* __restrict__ h_bf,
    const unsigned short* __restrict__ Bpre, const float* __restrict__ biasPre,
    unsigned short* __restrict__ Qt, float* __restrict__ Sb, int N)
{
    __shared__ __attribute__((aligned(16))) char smem[128 * 72 * 2 * 2];
    gemm_pre_tile(h_bf, Bpre, biasPre, Qt, Sb, N,
                  blockIdx.x / (NCP / 128), blockIdx.x % (NCP / 128), smem);
}

__global__ void scatter_kernel(const int* __restrict__ src, const int* __restrict__ dst,
                               const int* __restrict__ row_ptr, int* __restrict__ cursor,
                               int* __restrict__ csr_src, int E) {
    int e = blockIdx.x * blockDim.x + threadIdx.x;
    if (e < E) {
        int d = dst[e];
        int pos = atomicAdd(&cursor[d], 1);
        csr_src[row_ptr[d] + pos] = src[e];
    }
}

// ---------------------------------------------------------------------------
// One-pass flash attention aggregation (verified round 8, unchanged)
// ---------------------------------------------------------------------------
__global__ __launch_bounds__(256) void attn_agg(
    const unsigned short* __restrict__ Qt,
    const unsigned short* __restrict__ Hb,
    const int* __restrict__ row_ptr,
    const int* __restrict__ csr_src,
    unsigned short* __restrict__ Agg,
    int N)
{
    const int tid = threadIdx.x;
    const int wave = tid >> 6;
    const int g = (tid >> 4) & 3;
    const int l16 = tid & 15;
    const int node = blockIdx.x * 4 + wave;
    if (node >= N) return;

    const float NEG = -3e38f;

    float qf[4][8];
#pragma unroll
    for (int h = 0; h < 4; ++h) {
        bf16x8 qv = *(const bf16x8*)(Qt + (size_t)node * HF + h * F + l16 * 8);
#pragma unroll
        for (int j = 0; j < 8; ++j) qf[h][j] = bf2f((unsigned short)qv[j]);
    }
    const unsigned short* Hl = Hb + (size_t)l16 * 8;

    const int beg = row_ptr[node];
    const int end = row_ptr[node + 1];

    float m[4], z[4], acc[4][8];
#pragma unroll
    for (int h = 0; h < 4; ++h) { m[h] = NEG; z[h] = 0.f; }
#pragma unroll
    for (int h = 0; h < 4; ++h)
#pragma unroll
        for (int j = 0; j < 8; ++j) acc[h][j] = 0.f;

    for (int base = beg + g; base < end; base += 16) {
        const int i1 = base + 4, i2 = base + 8, i3 = base + 12;
        const bool v1 = i1 < end, v2 = i2 < end, v3 = i3 < end;
        int s0 = csr_src[base];
        int s1 = csr_src[v1 ? i1 : base];
        int s2 = csr_src[v2 ? i2 : base];
        int s3 = csr_src[v3 ? i3 : base];
        bf16x8 hb0 = *(const bf16x8*)(Hl + (size_t)s0 * F);
        bf16x8 hb1 = *(const bf16x8*)(Hl + (size_t)s1 * F);
        bf16x8 hb2 = *(const bf16x8*)(Hl + (size_t)s2 * F);
        bf16x8 hb3 = *(const bf16x8*)(Hl + (size_t)s3 * F);
        float hf[4][8];
#pragma unroll
        for (int j = 0; j < 8; ++j) {
            hf[0][j] = bf2f((unsigned short)hb0[j]);
            hf[1][j] = bf2f((unsigned short)hb1[j]);
            hf[2][j] = bf2f((unsigned short)hb2[j]);
            hf[3][j] = bf2f((unsigned short)hb3[j]);
        }
        float p[4][4];
#pragma unroll
        for (int e = 0; e < 4; ++e)
#pragma unroll
            for (int h = 0; h < 4; ++h) {
                float tv = 0.f;
#pragma unroll
                for (int j = 0; j < 8; ++j) tv += qf[h][j] * hf[e][j];
                p[e][h] = tv;
            }
#pragma unroll
        for (int off = 1; off < 16; off <<= 1)
#pragma unroll
            for (int e = 0; e < 4; ++e)
#pragma unroll
                for (int h = 0; h < 4; ++h)
                    p[e][h] += __shfl_xor(p[e][h], off, 64);
#pragma unroll
        for (int h = 0; h < 4; ++h) {
            if (!v1) p[1][h] = NEG;
            if (!v2) p[2][h] = NEG;
            if (!v3) p[3][h] = NEG;
        }
#pragma unroll
        for (int h = 0; h < 4; ++h) {
            float bm = fmaxf(fmaxf(p[0][h], p[1][h]), fmaxf(p[2][h], p[3][h]));
            float mn = fmaxf(m[h], bm);
            float rs = __expf(m[h] - mn);
            float w0 = __expf(p[0][h] - mn);
            float w1 = __expf(p[1][h] - mn);
            float w2 = __expf(p[2][h] - mn);
            float w3 = __expf(p[3][h] - mn);
            z[h] = z[h] * rs + (w0 + w1) + (w2 + w3);
#pragma unroll
            for (int j = 0; j < 8; ++j)
                acc[h][j] = acc[h][j] * rs
                          + w0 * hf[0][j] + w1 * hf[1][j]
                          + w2 * hf[2][j] + w3 * hf[3][j];
            m[h] = mn;
        }
    }

#pragma unroll
    for (int off = 16; off <= 32; off <<= 1) {
#pragma unroll
        for (int h = 0; h < 4; ++h) {
            float om = __shfl_xor(m[h], off, 64);
            float oz = __shfl_xor(z[h], off, 64);
            float M = fmaxf(m[h], om);
            float a = __expf(m[h] - M);
            float b = __expf(om - M);
            z[h] = z[h] * a + oz * b;
#pragma unroll
            for (int j = 0; j < 8; ++j) {
                float oa = __shfl_xor(acc[h][j], off, 64);
                acc[h][j] = acc[h][j] * a + oa * b;
            }
            m[h] = M;
        }
    }

    float i0 = (z[0] > 0.f) ? 1.f / z[0] : 0.f;
    float i1 = (z[1] > 0.f) ? 1.f / z[1] : 0.f;
    float i2 = (z[2] > 0.f) ? 1.f / z[2] : 0.f;
    float i3 = (z[3] > 0.f) ? 1.f / z[3] : 0.f;
    bf16x8 o;
    if (g == 0) {
#pragma unroll
        for (int j = 0; j < 8; ++j) o[j] = (short)f2bf(acc[0][j] * i0);
    } else if (g == 1) {
#pragma unroll
        for (int j = 0; j < 8; ++j) o[j] = (short)f2bf(acc[1][j] * i1);
    } else if (g == 2) {
#pragma unroll
        for (int j = 0; j < 8; ++j) o[j] = (short)f2bf(acc[2][j] * i2);
    } else {
#pragma unroll
        for (int j = 0; j < 8; ++j) o[j] = (short)f2bf(acc[3][j] * i3);
    }
    *(bf16x8*)(Agg + (size_t)node * HF + g * F + l16 * 8) = o;
}

// ---------------------------------------------------------------------------
// GEMM-post (round 8 version): out = Agg@Bpost^T + biasPost + Sb, (ReLU)
// grid (2, rowBlocks64) = 314 blocks
// ---------------------------------------------------------------------------
__global__ __launch_bounds__(256) void gemm_post(
    const unsigned short* __restrict__ Agg,   // [M][512] bf16
    const unsigned short* __restrict__ Bt,    // [128][512] bf16
    const float* __restrict__ bias,           // [128]
    const float* __restrict__ Sb,             // [M][128]
    float* __restrict__ out_f,
    unsigned short* __restrict__ out_bf,
    int relu, int M)
{
    __shared__ __attribute__((aligned(16))) unsigned short Stg[128 * 72];
    typedef unsigned short (*t64)[72];
    t64 As = (t64)Stg;
    t64 Bs = (t64)(Stg + 64 * 72);

    const int tid = threadIdx.x;
    const int wave = tid >> 6, lane = tid & 63;
    const int lane16 = lane & 15, quad = lane >> 4;
    const int row0 = blockIdx.y * 64;
    const int col0 = blockIdx.x * 64;

    f32x4 acc[4] = {};

    for (int kk = 0; kk < 512; kk += 64) {
#pragma unroll
        for (int rep = 0; rep < 2; ++rep) {
            int c = tid + rep * 256;
            int r = c >> 3, c8 = (c & 7) * 8;
            bf16x8 v = {};
            if (row0 + r < M) v = *(const bf16x8*)(Agg + (size_t)(row0 + r) * 512 + kk + c8);
            *(bf16x8*)&As[r][c8] = v;
            *(bf16x8*)&Bs[r][c8] = *(const bf16x8*)(Bt + (size_t)(col0 + r) * 512 + kk + c8);
        }
        __syncthreads();

#pragma unroll
        for (int ks = 0; ks < 2; ++ks) {
            bf16x8 b = *(const bf16x8*)&Bs[wave * 16 + lane16][ks * 32 + quad * 8];
#pragma unroll
            for (int mt = 0; mt < 4; ++mt) {
                bf16x8 a = *(const bf16x8*)&As[mt * 16 + lane16][ks * 32 + quad * 8];
                acc[mt] = __builtin_amdgcn_mfma_f32_16x16x32_bf16(a, b, acc[mt], 0, 0, 0);
            }
        }
        __syncthreads();
    }

    const int col = col0 + wave * 16 + lane16;
    const float bcol = bias[col];
#pragma unroll
    for (int mt = 0; mt < 4; ++mt) {
#pragma unroll
        for (int r = 0; r < 4; ++r) {
            int row = row0 + mt * 16 + quad * 4 + r;
            if (row < M) {
                float v = acc[mt][r] + bcol + Sb[(size_t)row * 128 + col];
                if (relu) v = fmaxf(v, 0.f);
                if (out_f)  out_f[(size_t)row * 128 + col] = v;
                if (out_bf) out_bf[(size_t)row * 128 + col] = f2bf(v);
            }
        }
    }
}

// ---------------------------------------------------------------------------
// Launch: 15 dispatches, every kernel >= 314 blocks
// ---------------------------------------------------------------------------
extern "C" void kernel_launch(void* const* d_in, const int* in_sizes, int n_in,
                              void* d_out, int out_size, void* d_ws, size_t ws_size,
                              hipStream_t stream) {
    const float* x     = (const float*)d_in[0];
    const int*   ei    = (const int*)d_in[1];
    const float* Wq    = (const float*)d_in[2];
    const float* bq    = (const float*)d_in[3];
    const float* Wk    = (const float*)d_in[4];
    const float* Wv    = (const float*)d_in[6];
    const float* bv    = (const float*)d_in[7];
    const float* Wskip = (const float*)d_in[8];
    const float* bskip = (const float*)d_in[9];
    float* out = (float*)d_out;

    const int N = in_sizes[0] / F;       // 10000
    const int E = in_sizes[1] / 2;       // 160000
    const float scale = 0.08838834764831845f;   // 1/sqrt(128)

    const int* src = ei;
    const int* dst = ei + E;

    // Workspace layout
    char* p = (char*)d_ws;
    float* Sb       = (float*)p;               p += (size_t)N * F * sizeof(float);
    float* biasPreP = (float*)p;               p += (size_t)LAYERS * NCP * sizeof(float);
    float* biasPostP= (float*)p;               p += (size_t)LAYERS * 128 * sizeof(float);
    unsigned short* h_bf  = (unsigned short*)p; p += (size_t)N * F * sizeof(unsigned short);
    unsigned short* Qt    = (unsigned short*)p; p += (size_t)N * HF * sizeof(unsigned short);
    unsigned short* AggB  = (unsigned short*)p; p += (size_t)N * HF * sizeof(unsigned short);
    unsigned short* BpreP = (unsigned short*)p; p += (size_t)LAYERS * NCP * 128 * sizeof(unsigned short);
    unsigned short* BpostP= (unsigned short*)p; p += (size_t)LAYERS * 128 * 512 * sizeof(unsigned short);
    int* deg     = (int*)p;                    p += (size_t)2 * N * sizeof(int);   // deg | cursor
    int* row_ptr = (int*)p;                    p += (size_t)(N + 1) * sizeof(int);
    int* csr_src = (int*)p;

    int* cursor = deg + N;

    // 1. zero deg+cursor
    hipMemsetAsync(deg, 0, 2 * (size_t)N * sizeof(int), stream);

    // 2. prep (converts, weight packs, biases) + hist
    prep_hist_kernel<<<NB_PREP, 256, 0, stream>>>(
        x, h_bf, N * F / 4, Wq, Wk, Wv, Wskip, bq, bskip, bv,
        BpreP, BpostP, biasPreP, biasPostP, dst, deg, E, scale);

    const int rowBlocks128 = (N + 127) / 128;
    const int rowBlocks64  = (N + 63) / 64;
    const int preTiles = rowBlocks128 * (NCP / 128);
    const int attnBlocks = (N + 3) / 4;

    // 3. scan (block 0) + layer-0 pre-GEMM
    scan_pre0_kernel<<<preTiles + 1, 256, 0, stream>>>(
        deg, row_ptr, N, h_bf, BpreP, biasPreP, Qt, Sb);

    // 4. scatter
    scatter_kernel<<<(E + 255) / 256, 256, 0, stream>>>(src, dst, row_ptr, cursor, csr_src, E);

    // 5. attention layer 0
    attn_agg<<<attnBlocks, 256, 0, stream>>>(Qt, h_bf, row_ptr, csr_src, AggB, N);

    // 6..14: (post_l -> pre_{l+1} -> attn_{l+1}) x3
    for (int l = 0; l < LAYERS - 1; ++l) {
        gemm_post<<<dim3(2, rowBlocks64), 256, 0, stream>>>(
            AggB, BpostP + (size_t)l * 128 * 512, biasPostP + (size_t)l * 128,
            Sb, nullptr, h_bf, 1, N);
        gemm_pre_kernel<<<preTiles, 256, 0, stream>>>(
            h_bf, BpreP + (size_t)(l + 1) * NCP * 128, biasPreP + (size_t)(l + 1) * NCP,
            Qt, Sb, N);
        attn_agg<<<attnBlocks, 256, 0, stream>>>(Qt, h_bf, row_ptr, csr_src, AggB, N);
    }

    // 15. final post (no ReLU, fp32 out)
    gemm_post<<<dim3(2, rowBlocks64), 256, 0, stream>>>(
        AggB, BpostP + (size_t)3 * 128 * 512, biasPostP + (size_t)3 * 128,
        Sb, out, nullptr, 0, N);
}

// Round 13
// 384.695 us; speedup vs baseline: 2.7871x; 1.1173x over previous
//
#include <hip/hip_runtime.h>
#include <math.h>

static constexpr int F  = 128;    // channels per head / input dim
static constexpr int H  = 4;      // heads
static constexpr int HF = 512;    // H*F
static constexpr int NCP = 640;   // pre-GEMM cols: q-tilde(512) | S(128)
static constexpr int LAYERS = 4;

typedef __attribute__((ext_vector_type(8))) short bf16x8;   // 8 bf16 (4 VGPRs)
typedef __attribute__((ext_vector_type(4))) float f32x4;

__device__ __forceinline__ unsigned short f2bf(float f) {
    union { float f; unsigned u; } v; v.f = f;
    unsigned r = (v.u + 0x7FFFu + ((v.u >> 16) & 1u)) >> 16;  // RNE
    return (unsigned short)r;
}
__device__ __forceinline__ float bf2f(unsigned short b) {
    union { unsigned u; float f; } v; v.u = ((unsigned)b) << 16;
    return v.f;
}

// ---------------------------------------------------------------------------
// CSR build (counting sort of edges by dst)
// ---------------------------------------------------------------------------
__global__ void hist_kernel(const int* __restrict__ dst, int* __restrict__ deg, int E) {
    int e = blockIdx.x * blockDim.x + threadIdx.x;
    if (e < E) atomicAdd(&deg[dst[e]], 1);
}

__global__ void scan_kernel(const int* __restrict__ deg, int* __restrict__ row_ptr, int n) {
    __shared__ int wsum[16];
    __shared__ int carry_s, wtot_s;
    const int tid = threadIdx.x;
    const int lane = tid & 63;
    const int wid = tid >> 6;
    if (tid == 0) { carry_s = 0; row_ptr[0] = 0; }
    __syncthreads();
    for (int base = 0; base < n; base += 1024) {
        int i = base + tid;
        int x = (i < n) ? deg[i] : 0;
#pragma unroll
        for (int off = 1; off < 64; off <<= 1) {
            int t = __shfl_up(x, off, 64);
            if (lane >= off) x += t;
        }
        if (lane == 63) wsum[wid] = x;
        __syncthreads();
        if (tid == 0) {
            int s = 0;
#pragma unroll
            for (int j = 0; j < 16; ++j) { int t = wsum[j]; wsum[j] = s; s += t; }
            wtot_s = s;
        }
        __syncthreads();
        int incl = x + wsum[wid] + carry_s;
        if (i < n) row_ptr[i + 1] = incl;
        __syncthreads();
        if (tid == 0) carry_s += wtot_s;
        __syncthreads();
    }
}

__global__ void scatter_kernel(const int* __restrict__ src, const int* __restrict__ dst,
                               const int* __restrict__ row_ptr, int* __restrict__ cursor,
                               int* __restrict__ csr_src, int E) {
    int e = blockIdx.x * blockDim.x + threadIdx.x;
    if (e < E) {
        int d = dst[e];
        int pos = atomicAdd(&cursor[d], 1);
        csr_src[row_ptr[d] + pos] = src[e];
    }
}

// ---------------------------------------------------------------------------
// Merged one-time prep: convert | wqk | pack_ws | pack_bpost | bias
// dispatched by 1-D block-index ranges.
// ---------------------------------------------------------------------------
static constexpr int NB_CONV  = 1250;   // N*F/4 / 256
static constexpr int NB_WQK   = 64;     // 2 x 2 x (L*H)
static constexpr int NB_WS    = 64;     // 4 x 4 x L
static constexpr int NB_BPOST = 256;    // 4 x 4 x (L*H)
static constexpr int NB_BIAS  = LAYERS;
static constexpr int NB_PREP  = NB_CONV + NB_WQK + NB_WS + NB_BPOST + NB_BIAS;

__global__ __launch_bounds__(256) void prep_kernel(
    const float* __restrict__ x, unsigned short* __restrict__ h_bf, int n4,
    const float* __restrict__ Wq, const float* __restrict__ Wk,
    const float* __restrict__ Wv, const float* __restrict__ Ws,
    const float* __restrict__ bq, const float* __restrict__ bs, const float* __restrict__ bv,
    unsigned short* __restrict__ Bpre, unsigned short* __restrict__ Bpost,
    float* __restrict__ biasPre, float* __restrict__ biasPost, float scale)
{
    __shared__ __attribute__((aligned(16))) float smem[64 * 33 * 2];   // 16.9 KB, reused by tasks
    const int tid = threadIdx.x;
    int b = blockIdx.x;

    if (b < NB_CONV) {
        // ---- convert x -> bf16
        int i = b * 256 + tid;
        if (i < n4) {
            float4 v = *(const float4*)(x + (size_t)i * 4);
            ushort4 o;
            o.x = f2bf(v.x); o.y = f2bf(v.y); o.z = f2bf(v.z); o.w = f2bf(v.w);
            *(ushort4*)(h_bf + (size_t)i * 4) = o;
        }
        return;
    }
    b -= NB_CONV;
    if (b < NB_WQK) {
        // ---- Wqk composite: Bpre[l][h*128+c][k] = scale * Wq[l][:,h]_k . Wk[l][:,h]_c
        float (*As)[33] = (float (*)[33])smem;            // Wk rows (c)
        float (*Bs)[33] = (float (*)[33])(smem + 64 * 33);// Wq rows (k)
        const int bx = b & 1, by = (b >> 1) & 1, lh = b >> 2;
        const int l = lh >> 2, h = lh & 3;
        const int c0 = by * 64, k0 = bx * 64;
        const float* Ab = Wk + (size_t)l * 65536 + h * 128;
        const float* Bb = Wq + (size_t)l * 65536 + h * 128;
        const int tx = tid & 15, ty = tid >> 4;
        float acc[4][4] = {};
        for (int jj = 0; jj < 128; jj += 32) {
#pragma unroll
            for (int rep = 0; rep < 2; ++rep) {
                int f = tid + rep * 256;
                int r = f >> 3, j4 = (f & 7) * 4;
                float4 a = *(const float4*)(Ab + (size_t)(c0 + r) * 512 + jj + j4);
                As[r][j4 + 0] = a.x; As[r][j4 + 1] = a.y; As[r][j4 + 2] = a.z; As[r][j4 + 3] = a.w;
                float4 bb = *(const float4*)(Bb + (size_t)(k0 + r) * 512 + jj + j4);
                Bs[r][j4 + 0] = bb.x; Bs[r][j4 + 1] = bb.y; Bs[r][j4 + 2] = bb.z; Bs[r][j4 + 3] = bb.w;
            }
            __syncthreads();
#pragma unroll
            for (int j = 0; j < 32; ++j) {
                float a0 = As[ty * 4 + 0][j], a1 = As[ty * 4 + 1][j];
                float a2 = As[ty * 4 + 2][j], a3 = As[ty * 4 + 3][j];
                float b0 = Bs[tx * 4 + 0][j], b1 = Bs[tx * 4 + 1][j];
                float b2 = Bs[tx * 4 + 2][j], b3 = Bs[tx * 4 + 3][j];
                acc[0][0] += a0 * b0; acc[0][1] += a0 * b1; acc[0][2] += a0 * b2; acc[0][3] += a0 * b3;
                acc[1][0] += a1 * b0; acc[1][1] += a1 * b1; acc[1][2] += a1 * b2; acc[1][3] += a1 * b3;
                acc[2][0] += a2 * b0; acc[2][1] += a2 * b1; acc[2][2] += a2 * b2; acc[2][3] += a2 * b3;
                acc[3][0] += a3 * b0; acc[3][1] += a3 * b1; acc[3][2] += a3 * b2; acc[3][3] += a3 * b3;
            }
            __syncthreads();
        }
#pragma unroll
        for (int i = 0; i < 4; ++i)
#pragma unroll
            for (int t = 0; t < 4; ++t) {
                int c = c0 + ty * 4 + i;
                int k = k0 + tx * 4 + t;
                Bpre[(size_t)l * NCP * 128 + (size_t)(h * 128 + c) * 128 + k] = f2bf(scale * acc[i][t]);
            }
        return;
    }
    b -= NB_WQK;
    if (b < NB_WS) {
        // ---- pack skip weights: Bpre[l][512+n][k] = Ws[l][k][n]
        unsigned short (*t)[33] = (unsigned short (*)[33])smem;
        const int bx = b & 3, by = (b >> 2) & 3, l = b >> 4;
        const int k0 = bx * 32, n0 = by * 32;
        const int cx = tid & 31, ry = tid >> 5;
#pragma unroll
        for (int rr = 0; rr < 32; rr += 8) {
            int k = k0 + ry + rr;
            t[ry + rr][cx] = f2bf(Ws[(size_t)l * 16384 + (size_t)k * 128 + n0 + cx]);
        }
        __syncthreads();
#pragma unroll
        for (int rr = 0; rr < 32; rr += 8) {
            int n = n0 + ry + rr;
            Bpre[(size_t)l * NCP * 128 + (size_t)(512 + n) * 128 + k0 + cx] = t[cx][ry + rr];
        }
        return;
    }
    b -= NB_WS;
    if (b < NB_BPOST) {
        // ---- pack post weights: Bpost[l][co][h*128+ci] = 0.25*Wv[l][ci][h*128+co]
        unsigned short (*t)[33] = (unsigned short (*)[33])smem;
        const int bx = b & 3, by = (b >> 2) & 3, lh = b >> 4;
        const int l = lh >> 2, h = lh & 3;
        const int ci0 = bx * 32, co0 = by * 32;
        const int cx = tid & 31, ry = tid >> 5;
#pragma unroll
        for (int rr = 0; rr < 32; rr += 8) {
            int ci = ci0 + ry + rr;
            t[ry + rr][cx] = f2bf(0.25f * Wv[(size_t)l * 65536 + (size_t)ci * 512 + h * 128 + co0 + cx]);
        }
        __syncthreads();
#pragma unroll
        for (int rr = 0; rr < 32; rr += 8) {
            int co = co0 + ry + rr;
            Bpost[(size_t)l * 65536 + (size_t)co * 512 + h * 128 + ci0 + cx] = t[cx][ry + rr];
        }
        return;
    }
    b -= NB_BPOST;
    {
        // ---- biases for layer l = b
        const int l = b;
        for (int n = tid; n < NCP; n += 256) {
            float v;
            if (n < 512) {
                int h = n >> 7, c = n & 127;
                float s = 0.f;
                for (int j = 0; j < 128; ++j)
                    s += bq[(size_t)l * 512 + h * 128 + j] * Wk[(size_t)l * 65536 + (size_t)c * 512 + h * 128 + j];
                v = s * scale;
            } else {
                v = bs[(size_t)l * 128 + (n - 512)];
            }
            biasPre[(size_t)l * NCP + n] = v;
        }
        for (int c = tid; c < 128; c += 256) {
            float s = 0.f;
            for (int h = 0; h < 4; ++h) s += bv[(size_t)l * 512 + h * 128 + c];
            biasPost[(size_t)l * 128 + c] = 0.25f * s;
        }
    }
}

// ---------------------------------------------------------------------------
// GEMM-pre: [M x 640] = h[M x 128] @ Bpre^T + biasPre.
// cols<512 -> q-tilde (bf16); cols>=512 -> S (fp32). 128x128 tiles.
// ---------------------------------------------------------------------------
__global__ __launch_bounds__(256) void gemm_pre(
    const unsigned short* __restrict__ Abf,   // [M][128] bf16
    const unsigned short* __restrict__ Bt,    // [640][128] bf16
    const float* __restrict__ bias,           // [640]
    unsigned short* __restrict__ Qt,          // [M][512] bf16
    float* __restrict__ Sb,                   // [M][128] fp32
    int M)
{
    __shared__ unsigned short As[128][72];
    __shared__ unsigned short Bs[128][72];

    const int tid = threadIdx.x;
    const int wave = tid >> 6, lane = tid & 63;
    const int lane16 = lane & 15, quad = lane >> 4;
    const int wr = wave >> 1, wc = wave & 1;
    const int row0 = blockIdx.y * 128;
    const int col0 = blockIdx.x * 128;

    f32x4 acc[4][4] = {};

    for (int kk = 0; kk < 128; kk += 64) {
#pragma unroll
        for (int j = 0; j < 4; ++j) {
            int c = tid + j * 256;
            int r = c >> 3, c8 = (c & 7) * 8;
            bf16x8 v = {};
            if (row0 + r < M) v = *(const bf16x8*)(Abf + (size_t)(row0 + r) * 128 + kk + c8);
            *(bf16x8*)&As[r][c8] = v;
        }
#pragma unroll
        for (int j = 0; j < 4; ++j) {
            int c = tid + j * 256;
            int r = c >> 3, c8 = (c & 7) * 8;
            *(bf16x8*)&Bs[r][c8] = *(const bf16x8*)(Bt + (size_t)(col0 + r) * 128 + kk + c8);
        }
        __syncthreads();

#pragma unroll
        for (int ks = 0; ks < 2; ++ks) {
            bf16x8 a[4], b[4];
#pragma unroll
            for (int i = 0; i < 4; ++i)
                a[i] = *(const bf16x8*)&As[wr * 64 + i * 16 + lane16][ks * 32 + quad * 8];
#pragma unroll
            for (int i = 0; i < 4; ++i)
                b[i] = *(const bf16x8*)&Bs[wc * 64 + i * 16 + lane16][ks * 32 + quad * 8];
#pragma unroll
            for (int mi = 0; mi < 4; ++mi)
#pragma unroll
                for (int ni = 0; ni < 4; ++ni)
                    acc[mi][ni] = __builtin_amdgcn_mfma_f32_16x16x32_bf16(
                        a[mi], b[ni], acc[mi][ni], 0, 0, 0);
        }
        __syncthreads();
    }

#pragma unroll
    for (int mi = 0; mi < 4; ++mi) {
        int rowb = row0 + wr * 64 + mi * 16 + quad * 4;
#pragma unroll
        for (int ni = 0; ni < 4; ++ni) {
            int col = col0 + wc * 64 + ni * 16 + lane16;
            float bv = bias[col];
#pragma unroll
            for (int r = 0; r < 4; ++r) {
                int gr = rowb + r;
                if (gr < M) {
                    float v = acc[mi][ni][r] + bv;
                    if (col < 512) Qt[(size_t)gr * 512 + col] = f2bf(v);
                    else           Sb[(size_t)gr * 128 + (col - 512)] = v;
                }
            }
        }
    }
}

// ---------------------------------------------------------------------------
// ONE-PASS flash attention aggregation: wave = node; 16-lane group g owns
// edge positions beg+g, beg+g+4, ... (stride 4) and keeps private running
// (m,z,acc) for ALL 4 heads over its subset. Per batch of 4 edges: 4
// independent gathers in flight, 16 logits, one flash update, aggregation
// straight from registers (single gather per edge, no LDS). Group partials
// merged at the end with a butterfly flash-combine.
// ---------------------------------------------------------------------------
__global__ __launch_bounds__(256) void attn_agg(
    const unsigned short* __restrict__ Qt,   // [N][512] bf16 (scale+bqk folded)
    const unsigned short* __restrict__ Hb,   // [N][128] bf16
    const int* __restrict__ row_ptr,
    const int* __restrict__ csr_src,
    unsigned short* __restrict__ Agg,        // [N][512] bf16
    int N)
{
    const int tid = threadIdx.x;
    const int wave = tid >> 6;
    const int g = (tid >> 4) & 3;
    const int l16 = tid & 15;
    const int node = blockIdx.x * 4 + wave;
    if (node >= N) return;

    const float NEG = -3e38f;   // finite sentinel: exp(NEG - finite) == 0, no NaN

    // q-tilde for all 4 heads, this lane's 8 channels (same across groups -> L1 broadcast)
    float qf[4][8];
#pragma unroll
    for (int h = 0; h < 4; ++h) {
        bf16x8 qv = *(const bf16x8*)(Qt + (size_t)node * HF + h * F + l16 * 8);
#pragma unroll
        for (int j = 0; j < 8; ++j) qf[h][j] = bf2f((unsigned short)qv[j]);
    }
    const unsigned short* Hl = Hb + (size_t)l16 * 8;

    const int beg = row_ptr[node];
    const int end = row_ptr[node + 1];

    float m[4], z[4], acc[4][8];
#pragma unroll
    for (int h = 0; h < 4; ++h) { m[h] = NEG; z[h] = 0.f; }
#pragma unroll
    for (int h = 0; h < 4; ++h)
#pragma unroll
        for (int j = 0; j < 8; ++j) acc[h][j] = 0.f;

    for (int base = beg + g; base < end; base += 16) {
        // slot 0 always valid; clamp invalid slots to a valid position
        const int i1 = base + 4, i2 = base + 8, i3 = base + 12;
        const bool v1 = i1 < end, v2 = i2 < end, v3 = i3 < end;
        int s0 = csr_src[base];
        int s1 = csr_src[v1 ? i1 : base];
        int s2 = csr_src[v2 ? i2 : base];
        int s3 = csr_src[v3 ? i3 : base];
        // 4 independent gathers in flight
        bf16x8 hb0 = *(const bf16x8*)(Hl + (size_t)s0 * F);
        bf16x8 hb1 = *(const bf16x8*)(Hl + (size_t)s1 * F);
        bf16x8 hb2 = *(const bf16x8*)(Hl + (size_t)s2 * F);
        bf16x8 hb3 = *(const bf16x8*)(Hl + (size_t)s3 * F);
        float hf[4][8];
#pragma unroll
        for (int j = 0; j < 8; ++j) {
            hf[0][j] = bf2f((unsigned short)hb0[j]);
            hf[1][j] = bf2f((unsigned short)hb1[j]);
            hf[2][j] = bf2f((unsigned short)hb2[j]);
            hf[3][j] = bf2f((unsigned short)hb3[j]);
        }
        // 16 logits (4 slots x 4 heads), partial per lane
        float p[4][4];
#pragma unroll
        for (int e = 0; e < 4; ++e)
#pragma unroll
            for (int h = 0; h < 4; ++h) {
                float t = 0.f;
#pragma unroll
                for (int j = 0; j < 8; ++j) t += qf[h][j] * hf[e][j];
                p[e][h] = t;
            }
        // reduce within 16-lane group
#pragma unroll
        for (int off = 1; off < 16; off <<= 1)
#pragma unroll
            for (int e = 0; e < 4; ++e)
#pragma unroll
                for (int h = 0; h < 4; ++h)
                    p[e][h] += __shfl_xor(p[e][h], off, 64);
        // mask invalid slots
#pragma unroll
        for (int h = 0; h < 4; ++h) {
            if (!v1) p[1][h] = NEG;
            if (!v2) p[2][h] = NEG;
            if (!v3) p[3][h] = NEG;
        }
        // flash update (one rescale per 4 edges)
#pragma unroll
        for (int h = 0; h < 4; ++h) {
            float bm = fmaxf(fmaxf(p[0][h], p[1][h]), fmaxf(p[2][h], p[3][h]));
            float mn = fmaxf(m[h], bm);
            float rs = __expf(m[h] - mn);
            float w0 = __expf(p[0][h] - mn);
            float w1 = __expf(p[1][h] - mn);
            float w2 = __expf(p[2][h] - mn);
            float w3 = __expf(p[3][h] - mn);
            z[h] = z[h] * rs + (w0 + w1) + (w2 + w3);
#pragma unroll
            for (int j = 0; j < 8; ++j)
                acc[h][j] = acc[h][j] * rs
                          + w0 * hf[0][j] + w1 * hf[1][j]
                          + w2 * hf[2][j] + w3 * hf[3][j];
            m[h] = mn;
        }
    }

    // merge group partials: butterfly flash-combine across groups (xor 16, 32)
#pragma unroll
    for (int off = 16; off <= 32; off <<= 1) {
#pragma unroll
        for (int h = 0; h < 4; ++h) {
            float om = __shfl_xor(m[h], off, 64);
            float oz = __shfl_xor(z[h], off, 64);
            float M = fmaxf(m[h], om);
            float a = __expf(m[h] - M);
            float b = __expf(om - M);
            z[h] = z[h] * a + oz * b;
#pragma unroll
            for (int j = 0; j < 8; ++j) {
                float oa = __shfl_xor(acc[h][j], off, 64);
                acc[h][j] = acc[h][j] * a + oa * b;
            }
            m[h] = M;
        }
    }

    // normalize + write: group g writes head g's 256 B slice
    float i0 = (z[0] > 0.f) ? 1.f / z[0] : 0.f;
    float i1 = (z[1] > 0.f) ? 1.f / z[1] : 0.f;
    float i2 = (z[2] > 0.f) ? 1.f / z[2] : 0.f;
    float i3 = (z[3] > 0.f) ? 1.f / z[3] : 0.f;
    bf16x8 o;
    if (g == 0) {
#pragma unroll
        for (int j = 0; j < 8; ++j) o[j] = (short)f2bf(acc[0][j] * i0);
    } else if (g == 1) {
#pragma unroll
        for (int j = 0; j < 8; ++j) o[j] = (short)f2bf(acc[1][j] * i1);
    } else if (g == 2) {
#pragma unroll
        for (int j = 0; j < 8; ++j) o[j] = (short)f2bf(acc[2][j] * i2);
    } else {
#pragma unroll
        for (int j = 0; j < 8; ++j) o[j] = (short)f2bf(acc[3][j] * i3);
    }
    *(bf16x8*)(Agg + (size_t)node * HF + g * F + l16 * 8) = o;
}

// ---------------------------------------------------------------------------
// GEMM-post: out[M x 128] = Agg[M x 512] @ Bpost^T + biasPost + S, (ReLU).
// ---------------------------------------------------------------------------
__global__ __launch_bounds__(256) void gemm_post(
    const unsigned short* __restrict__ Agg,   // [M][512] bf16
    const unsigned short* __restrict__ Bt,    // [128][512] bf16
    const float* __restrict__ bias,           // [128]
    const float* __restrict__ Sb,             // [M][128]
    float* __restrict__ out_f,
    unsigned short* __restrict__ out_bf,
    int relu, int M)
{
    __shared__ unsigned short As[64][72];
    __shared__ unsigned short Bs[64][72];

    const int tid = threadIdx.x;
    const int wave = tid >> 6, lane = tid & 63;
    const int lane16 = lane & 15, quad = lane >> 4;
    const int row0 = blockIdx.y * 64;
    const int col0 = blockIdx.x * 64;

    f32x4 acc[4] = {};

    for (int kk = 0; kk < 512; kk += 64) {
#pragma unroll
        for (int rep = 0; rep < 2; ++rep) {
            int c = tid + rep * 256;
            int r = c >> 3, c8 = (c & 7) * 8;
            bf16x8 v = {};
            if (row0 + r < M) v = *(const bf16x8*)(Agg + (size_t)(row0 + r) * 512 + kk + c8);
            *(bf16x8*)&As[r][c8] = v;
            *(bf16x8*)&Bs[r][c8] = *(const bf16x8*)(Bt + (size_t)(col0 + r) * 512 + kk + c8);
        }
        __syncthreads();

#pragma unroll
        for (int ks = 0; ks < 2; ++ks) {
            bf16x8 b = *(const bf16x8*)&Bs[wave * 16 + lane16][ks * 32 + quad * 8];
#pragma unroll
            for (int mt = 0; mt < 4; ++mt) {
                bf16x8 a = *(const bf16x8*)&As[mt * 16 + lane16][ks * 32 + quad * 8];
                acc[mt] = __builtin_amdgcn_mfma_f32_16x16x32_bf16(a, b, acc[mt], 0, 0, 0);
            }
        }
        __syncthreads();
    }

    const int col = col0 + wave * 16 + lane16;
    const float bcol = bias[col];
#pragma unroll
    for (int mt = 0; mt < 4; ++mt) {
#pragma unroll
        for (int r = 0; r < 4; ++r) {
            int row = row0 + mt * 16 + quad * 4 + r;
            if (row < M) {
                float v = acc[mt][r] + bcol + Sb[(size_t)row * 128 + col];
                if (relu) v = fmaxf(v, 0.f);
                if (out_f)  out_f[(size_t)row * 128 + col] = v;
                if (out_bf) out_bf[(size_t)row * 128 + col] = f2bf(v);
            }
        }
    }
}

// ---------------------------------------------------------------------------
// Launch
// ---------------------------------------------------------------------------
extern "C" void kernel_launch(void* const* d_in, const int* in_sizes, int n_in,
                              void* d_out, int out_size, void* d_ws, size_t ws_size,
                              hipStream_t stream) {
    const float* x     = (const float*)d_in[0];
    const int*   ei    = (const int*)d_in[1];
    const float* Wq    = (const float*)d_in[2];
    const float* bq    = (const float*)d_in[3];
    const float* Wk    = (const float*)d_in[4];
    const float* Wv    = (const float*)d_in[6];
    const float* bv    = (const float*)d_in[7];
    const float* Wskip = (const float*)d_in[8];
    const float* bskip = (const float*)d_in[9];
    float* out = (float*)d_out;

    const int N = in_sizes[0] / F;       // 10000
    const int E = in_sizes[1] / 2;       // 160000
    const float scale = 0.08838834764831845f;   // 1/sqrt(128)

    const int* src = ei;
    const int* dst = ei + E;

    // Workspace layout
    char* p = (char*)d_ws;
    float* Sb       = (float*)p;               p += (size_t)N * F * sizeof(float);
    float* biasPreP = (float*)p;               p += (size_t)LAYERS * NCP * sizeof(float);
    float* biasPostP= (float*)p;               p += (size_t)LAYERS * 128 * sizeof(float);
    unsigned short* h_bf  = (unsigned short*)p; p += (size_t)N * F * sizeof(unsigned short);
    unsigned short* Qt    = (unsigned short*)p; p += (size_t)N * HF * sizeof(unsigned short);
    unsigned short* AggB  = (unsigned short*)p; p += (size_t)N * HF * sizeof(unsigned short);
    unsigned short* BpreP = (unsigned short*)p; p += (size_t)LAYERS * NCP * 128 * sizeof(unsigned short);
    unsigned short* BpostP= (unsigned short*)p; p += (size_t)LAYERS * 128 * 512 * sizeof(unsigned short);
    int* deg     = (int*)p;                    p += (size_t)N * sizeof(int);
    int* cursor  = (int*)p;                    p += (size_t)N * sizeof(int);
    int* row_ptr = (int*)p;                    p += (size_t)(N + 1) * sizeof(int);
    int* csr_src = (int*)p;

    // --- CSR build
    hipMemsetAsync(deg, 0, 2 * (size_t)N * sizeof(int), stream);  // deg + cursor
    {
        int blocks = (E + 255) / 256;
        hist_kernel<<<blocks, 256, 0, stream>>>(dst, deg, E);
        scan_kernel<<<1, 1024, 0, stream>>>(deg, row_ptr, N);
        scatter_kernel<<<blocks, 256, 0, stream>>>(src, dst, row_ptr, cursor, csr_src, E);
    }

    // --- One-time prep (merged): convert | wqk | pack_ws | pack_bpost | bias
    prep_kernel<<<NB_PREP, 256, 0, stream>>>(x, h_bf, N * F / 4,
                                             Wq, Wk, Wv, Wskip,
                                             bq, bskip, bv,
                                             BpreP, BpostP, biasPreP, biasPostP, scale);

    const int rowBlocks128 = (N + 127) / 128;
    const int rowBlocks64  = (N + 63) / 64;
    const int attnBlocks   = (N + 3) / 4;

    for (int l = 0; l < LAYERS; ++l) {
        dim3 gridPre(NCP / 128, rowBlocks128);
        gemm_pre<<<gridPre, 256, 0, stream>>>(h_bf,
                                              BpreP + (size_t)l * NCP * 128,
                                              biasPreP + (size_t)l * NCP,
                                              Qt, Sb, N);

        attn_agg<<<attnBlocks, 256, 0, stream>>>(Qt, h_bf, row_ptr, csr_src, AggB, N);

        float* out_f = nullptr;
        unsigned short* out_bf = nullptr;
        int relu;
        if (l == LAYERS - 1) { out_f = out; relu = 0; }
        else { out_bf = h_bf; relu = 1; }

        dim3 gridPost(2, rowBlocks64);
        gemm_post<<<gridPost, 256, 0, stream>>>(AggB,
                                                BpostP + (size_t)l * 128 * 512,
                                                biasPostP + (size_t)l * 128,
                                                Sb, out_f, out_bf, relu, N);
    }
}